// Round 7
// baseline (1568.398 us; speedup 1.0000x reference)
//
#include <hip/hip_runtime.h>

typedef unsigned int uint;
typedef unsigned short ushort;

#define NB 32

// geometry
#define L1N 9216      // 96*96
#define ORGB 75
#define OGRAY 25
#define C1 100
#define C1P 128       // channel pad, layer-1 GEMM
#define PLANE1 2500   // 50*50 padded
#define P1 2304       // 48*48
#define M1 225
#define P2 576        // 24*24
#define M2 625
#define C2P 256       // channel pad, layer-2 GEMM (M1=225 -> 256)
#define N2 484        // 22*22
#define FCN 302500    // 625*484
#define NT1 73728     // 2304*32 merged columns
#define NT2 15488     // 484*32 merged columns

// exact ranks: ceil(percent*N) evaluated in fp64
#define KK0 345600u
#define KK1 115200u
#define KK2 207360u
#define KK3 121000u

// ---- workspace layout (float-element offsets) ----
constexpr size_t O_A     = 0;                       // Drgb 22,118,400 -> D1 16.6M -> D2 9.68M
constexpr size_t O_B     = 22118400;                // Dgray 7,372,800 ; W overlays after tri_sfm1
constexpr size_t O_W1H   = O_B;                     // 9*225*128 ushorts = 129,600 floats each
constexpr size_t O_W1M   = O_B + 129600;
constexpr size_t O_W1L   = O_B + 259200;
constexpr size_t O_W2H   = O_B + 388800;            // 9*625*256 ushorts = 720,000 floats each
constexpr size_t O_W2M   = O_B + 1108800;
constexpr size_t O_W2L   = O_B + 1828800;           // end 2,548,800 <= 7,372,800
constexpr size_t O_X     = 29491200;                // X' channel-last split planes
constexpr size_t O_X1H   = O_X;                     // 32*2500*128 ushorts = 5,120,000 floats each
constexpr size_t O_X1M   = O_X + 5120000;
constexpr size_t O_X1L   = O_X + 10240000;
constexpr size_t O_X2H   = O_X;                     // overlay: 32*576*256 ushorts = 2,359,296 floats
constexpr size_t O_X2M   = O_X + 2359296;
constexpr size_t O_X2L   = O_X + 4718592;
constexpr size_t O_HIST  = O_X + 15360000;          // 44,851,200 ; 65,536 uints
constexpr size_t O_STATE = O_HIST + 65536;          // 128 uint2
constexpr size_t O_THR   = O_STATE + 256;
constexpr size_t O_WSQ1  = O_THR + 128;
constexpr size_t O_WSQ2  = O_WSQ1 + 256;
constexpr size_t O_YMC1  = O_WSQ2 + 640;            // 73,728 ints (pre-scaled by C1P, batch-folded)
constexpr size_t O_OMAP1 = O_YMC1 + 73728;
constexpr size_t O_YMC2  = O_OMAP1 + 73728;         // 15,488
constexpr size_t O_OMAP2 = O_YMC2 + 15488;
constexpr size_t O_ZP1   = O_OMAP2 + 15488;         // 80,000
constexpr size_t O_PSQ1  = O_ZP1 + 80000;           // 73,728
constexpr size_t O_Z2    = O_PSQ1 + 73728;          // 18,432
constexpr size_t O_PSQ2  = O_Z2 + 18432;            // 15,488
constexpr size_t O_END   = O_PSQ2 + 15488;          // 45,284,096 floats = 181.1 MB

// ---- bf16 helpers (RNE) ----
__device__ __forceinline__ ushort bf16_rne(float x) {
    uint u = __float_as_uint(x);
    uint r = u + 0x7FFFu + ((u >> 16) & 1u);
    return (ushort)(r >> 16);
}
__device__ __forceinline__ float bf16_f32(ushort h) {
    return __uint_as_float(((uint)h) << 16);
}
__device__ __forceinline__ void split3(float v, ushort& h, ushort& m, ushort& l) {
    h = bf16_rne(v);           float hf = bf16_f32(h);
    m = bf16_rne(v - hf);      float mf = bf16_f32(m);
    l = bf16_rne(v - hf - mf);
}

typedef __attribute__((ext_vector_type(8))) short bf16x8;
typedef __attribute__((ext_vector_type(4))) float f32x4;

// ===================== init: zero hist, states, tables, out=bias =====================
__global__ void k_tables(float* ws, const float* fcb, float* out) {
    int i = blockIdx.x*256 + threadIdx.x;
    if (i < 65536) { ((uint*)(ws + O_HIST))[i] = 0u; return; }
    i -= 65536;
    if (i < NT1) {
        int b = i / P1, p = i % P1;
        ((int*)(ws + O_YMC1))[i]  = (b*PLANE1 + (p/48)*50 + (p%48)) * C1P;
        ((int*)(ws + O_OMAP1))[i] = b*(M1*P1) + p;
        return;
    }
    i -= NT1;
    if (i < NT2) {
        int b = i / N2, p = i % N2;
        ((int*)(ws + O_YMC2))[i]  = (b*P2 + (p/22)*24 + (p%22)) * C2P;
        ((int*)(ws + O_OMAP2))[i] = b*FCN + p;
        return;
    }
    i -= NT2;
    if (i < 320) { out[i] = fcb[i % 10]; return; }
    i -= 320;
    if (i < 128) {
        const uint kks[4] = {KK0, KK1, KK2, KK3};
        ((uint2*)(ws + O_STATE))[i] = make_uint2(0u, kks[i >> 5]);
    }
}

// ===================== per-row squared norms of conv weights =====================
__global__ void k_wsq(const float* c1w, const float* c2w, float* ws) {
    int o = blockIdx.x, lane = threadIdx.x;   // 64 threads
    const float* row; int K; float* dst;
    if (o < M1) { row = c1w + (size_t)o*900; K = 900; dst = ws + O_WSQ1 + o; }
    else { int oo = o - M1; row = c2w + (size_t)oo*2025; K = 2025; dst = ws + O_WSQ2 + oo; }
    float s = 0.f;
    for (int k = lane; k < K; k += 64) { float v = row[k]; s += v*v; }
    #pragma unroll
    for (int off = 32; off; off >>= 1) s += __shfl_down(s, off);
    if (lane == 0) *dst = s;
}

// ===================== split W into tap-major bf16 planes Wrs[9][M][C'] =====================
__global__ void k_splitw(const float* __restrict__ c1w, const float* __restrict__ c2w,
                         float* __restrict__ ws) {
    int i = blockIdx.x*256 + threadIdx.x;
    ushort h, m, l;
    if (i < 9*M1*C1P) {
        int rs = i / (M1*C1P), r2 = i % (M1*C1P);
        int mm = r2 / C1P, c = r2 % C1P;
        float x = (c < C1) ? c1w[(size_t)mm*900 + c*9 + rs] : 0.f;
        split3(x, h, m, l);
        ((ushort*)(ws + O_W1H))[i] = h;
        ((ushort*)(ws + O_W1M))[i] = m;
        ((ushort*)(ws + O_W1L))[i] = l;
        return;
    }
    i -= 9*M1*C1P;
    if (i < 9*M2*C2P) {
        int rs = i / (M2*C2P), r2 = i % (M2*C2P);
        int mm = r2 / C2P, c = r2 % C2P;
        float x = (c < M1) ? c2w[(size_t)mm*2025 + c*9 + rs] : 0.f;
        split3(x, h, m, l);
        ((ushort*)(ws + O_W2H))[i] = h;
        ((ushort*)(ws + O_W2M))[i] = m;
        ((ushort*)(ws + O_W2L))[i] = l;
    }
}

// ===================== stage 1: rgb distance =====================
__global__ void k_rgb_d(const float* __restrict__ x, const float* __restrict__ rgbw,
                        float* __restrict__ D) {
    __shared__ float lw[ORGB*3];
    __shared__ float lwsq[ORGB];
    int tid = threadIdx.x;
    if (tid < ORGB*3) lw[tid] = rgbw[tid];
    __syncthreads();
    if (tid < ORGB) {
        float a = lw[tid*3], b = lw[tid*3+1], c = lw[tid*3+2];
        lwsq[tid] = 25.0f*(a*a + b*b + c*c);
    }
    __syncthreads();
    int p = blockIdx.x*256 + tid;
    int b = blockIdx.y;
    int y = p / 96, xx = p % 96;
    const float* xb = x + (size_t)b*3*10000;
    float s1_0 = 0, s1_1 = 0, s1_2 = 0, s2 = 0;
    #pragma unroll
    for (int r = 0; r < 5; ++r)
        #pragma unroll
        for (int s = 0; s < 5; ++s) {
            int off = (y+r)*100 + (xx+s);
            float v0 = xb[off], v1 = xb[10000+off], v2 = xb[20000+off];
            s1_0 += v0; s1_1 += v1; s1_2 += v2;
            s2 += v0*v0 + v1*v1 + v2*v2;
        }
    float* Db = D + (size_t)b*ORGB*L1N + p;
    for (int o = 0; o < ORGB; ++o) {
        float dot = lw[o*3]*s1_0 + lw[o*3+1]*s1_1 + lw[o*3+2]*s1_2;
        float d2 = s2 + lwsq[o] - 2.0f*dot;
        Db[(size_t)o*L1N] = sqrtf(fmaxf(d2, 0.0f));
    }
}

// ===================== stage 1: gray distance =====================
__global__ void k_gray_d(const float* __restrict__ x, const float* __restrict__ gw,
                         float* __restrict__ D) {
    __shared__ float lw[625];
    __shared__ float lwsq[25];
    int tid = threadIdx.x;
    for (int i = tid; i < 625; i += 256) lw[i] = gw[i];
    __syncthreads();
    if (tid < 25) {
        float s = 0.f;
        for (int k = 0; k < 25; ++k) { float v = lw[tid*25+k]; s += v*v; }
        lwsq[tid] = s;
    }
    __syncthreads();
    int p = blockIdx.x*256 + tid;
    int b = blockIdx.y;
    int y = p / 96, xx = p % 96;
    const float* xb = x + (size_t)b*3*10000;
    float pv[25]; float psum = 0.f;
    #pragma unroll
    for (int r = 0; r < 5; ++r)
        #pragma unroll
        for (int s = 0; s < 5; ++s) {
            int off = (y+r)*100 + (xx+s);
            float g = 0.2989f*xb[off] + 0.587f*xb[10000+off] + 0.114f*xb[20000+off];
            pv[r*5+s] = g; psum += g*g;
        }
    float* Db = D + (size_t)b*OGRAY*L1N + p;
    for (int o = 0; o < 25; ++o) {
        float dot = 0.f;
        #pragma unroll
        for (int k = 0; k < 25; ++k) dot += lw[o*25+k]*pv[k];
        float d2 = psum + lwsq[o] - 2.0f*dot;
        Db[(size_t)o*L1N] = sqrtf(fmaxf(d2, 0.0f));
    }
}

// ===================== exact rank selection: histogram pass =====================
__global__ void k_hist(const float* __restrict__ d, int perBatch, uint* __restrict__ hist,
                       const uint2* __restrict__ state, int shift, uint pmask) {
    __shared__ uint lh[2048];
    int tid = threadIdx.x;
    for (int i = tid; i < 2048; i += 256) lh[i] = 0u;
    __syncthreads();
    int b = blockIdx.y;
    uint pref = state[b].x;
    const float* db = d + (size_t)b*perBatch;
    for (int i = blockIdx.x*256 + tid; i < perBatch; i += 256*32) {
        uint bits = __float_as_uint(db[i]);
        if ((bits & pmask) == pref)
            atomicAdd(&lh[(bits >> shift) & 2047u], 1u);
    }
    __syncthreads();
    uint* hb = hist + (size_t)b*2048;
    for (int i = tid; i < 2048; i += 256) {
        uint v = lh[i];
        if (v) atomicAdd(&hb[i], v);
    }
}

// ===================== selection: scan + state update (+zero hist) =====================
__global__ void k_scan(uint* __restrict__ hist, uint2* __restrict__ state, int shift,
                       int isFinal, float* __restrict__ thr_out, const float* __restrict__ wcap) {
    __shared__ uint ss[256];
    int b = blockIdx.x, t = threadIdx.x;
    uint* hb = hist + (size_t)b*2048;
    uint bins[8]; uint seg = 0;
    #pragma unroll
    for (int i = 0; i < 8; ++i) { bins[i] = hb[t*8+i]; seg += bins[i]; }
    ss[t] = seg;
    __syncthreads();
    for (int off = 1; off < 256; off <<= 1) {
        uint add = (t >= off) ? ss[t-off] : 0u;
        __syncthreads();
        ss[t] += add;
        __syncthreads();
    }
    uint incl = ss[t], excl = incl - seg;
    uint rank = state[b].y;
    if (excl < rank && rank <= incl) {
        uint c = excl;
        #pragma unroll
        for (int i = 0; i < 8; ++i) {
            c += bins[i];
            if (c >= rank) {
                uint bin = (uint)(t*8+i);
                uint pref = state[b].x | (bin << shift);
                if (isFinal) {
                    thr_out[b] = fminf(__uint_as_float(pref), wcap[0]);
                } else {
                    state[b] = make_uint2(pref, rank - (c - bins[i]));
                }
                break;
            }
        }
    }
    __syncthreads();
    #pragma unroll
    for (int i = 0; i < 8; ++i) hb[t*8+i] = 0u;
}

// ===================== triangle + concat + sfm(2,2) -> channel-last X1' splits =====================
// thread = (b, q in 2500, c-oct in 16): writes 8 channels as one 16B store per plane.
__global__ void k_tri_sfm1(const float* __restrict__ Drgb, const float* __restrict__ Dgray,
                           const float* __restrict__ thrA, const float* __restrict__ thrB,
                           const float* __restrict__ w1, ushort* __restrict__ XH,
                           ushort* __restrict__ XM, ushort* __restrict__ XL) {
    int idx = blockIdx.x*256 + threadIdx.x;   // 32*2500*16 = 1,280,000
    int oct = idx & 15;
    int rest = idx >> 4;                      // b*2500 + q
    int q = rest % PLANE1, b = rest / PLANE1;
    int pi = q / 50, pj = q % 50;
    bool border = (pi == 0 || pi == 49 || pj == 0 || pj == 49);
    float invw = 1.0f / w1[0];
    float tA = thrA[b], tB = thrB[b];
    int base = (2*(pi-1))*96 + 2*(pj-1);
    ushort h[8], m[8], l[8];
    #pragma unroll
    for (int j8 = 0; j8 < 8; ++j8) {
        int c = oct*8 + j8;
        float v = 0.f;
        if (!border && c < C1) {
            const float* src; float thr;
            if (c < ORGB) { src = Drgb + ((size_t)b*ORGB + c)*L1N; thr = tA; }
            else          { src = Dgray + ((size_t)b*OGRAY + (c-ORGB))*L1N; thr = tB; }
            float d00 = src[base], d01 = src[base+1], d10 = src[base+96], d11 = src[base+97];
            float t00 = d00 > thr ? 0.f : 1.f - d00*invw;
            float t01 = d01 > thr ? 0.f : 1.f - d01*invw;
            float t10 = d10 > thr ? 0.f : 1.f - d10*invw;
            float t11 = d11 > thr ? 0.f : 1.f - d11*invw;
            v = 0.25f*(0.9f*t00 + 0.93f*t01 + 0.96f*t10 + 0.99f*t11);
        }
        split3(v, h[j8], m[j8], l[j8]);
    }
    size_t ob = (size_t)rest * C1P + oct*8;
    uint4 ph, pm, pl;
    ph.x = (uint)h[0] | ((uint)h[1]<<16); ph.y = (uint)h[2] | ((uint)h[3]<<16);
    ph.z = (uint)h[4] | ((uint)h[5]<<16); ph.w = (uint)h[6] | ((uint)h[7]<<16);
    pm.x = (uint)m[0] | ((uint)m[1]<<16); pm.y = (uint)m[2] | ((uint)m[3]<<16);
    pm.z = (uint)m[4] | ((uint)m[5]<<16); pm.w = (uint)m[6] | ((uint)m[7]<<16);
    pl.x = (uint)l[0] | ((uint)l[1]<<16); pl.y = (uint)l[2] | ((uint)l[3]<<16);
    pl.z = (uint)l[4] | ((uint)l[5]<<16); pl.w = (uint)l[6] | ((uint)l[7]<<16);
    *(uint4*)&XH[ob] = ph; *(uint4*)&XM[ob] = pm; *(uint4*)&XL[ob] = pl;
}

// ===================== channel-sum of squares (padded plane, channel-last) =====================
__global__ void k_z1(const ushort* __restrict__ XH, const ushort* __restrict__ XM,
                     const ushort* __restrict__ XL, float* __restrict__ Zp) {
    int idx = blockIdx.x*256 + threadIdx.x;
    if (idx >= NB*PLANE1) return;
    size_t base = (size_t)idx * C1P;
    float s = 0.f;
    for (int oct = 0; oct < 16; ++oct) {
        uint4 ph = *(const uint4*)&XH[base + oct*8];
        uint4 pm = *(const uint4*)&XM[base + oct*8];
        uint4 pl = *(const uint4*)&XL[base + oct*8];
        const uint* hu = (const uint*)&ph; const uint* mu = (const uint*)&pm;
        const uint* lu = (const uint*)&pl;
        #pragma unroll
        for (int w = 0; w < 4; ++w) {
            float v0 = bf16_f32((ushort)(hu[w] & 0xFFFF)) + bf16_f32((ushort)(mu[w] & 0xFFFF))
                     + bf16_f32((ushort)(lu[w] & 0xFFFF));
            float v1 = bf16_f32((ushort)(hu[w] >> 16)) + bf16_f32((ushort)(mu[w] >> 16))
                     + bf16_f32((ushort)(lu[w] >> 16));
            s += v0*v0 + v1*v1;
        }
    }
    Zp[idx] = s;
}

__global__ void k_psq1(const float* __restrict__ Zp, float* __restrict__ psq) {
    int idx = blockIdx.x*256 + threadIdx.x;   // exactly 32*2304
    int b = idx / P1, p = idx % P1;
    int y = p / 48, x = p % 48;
    const float* zb = Zp + (size_t)b*PLANE1;
    float s = 0.f;
    #pragma unroll
    for (int r = 0; r < 3; ++r)
        #pragma unroll
        for (int c = 0; c < 3; ++c) s += zb[(y+r)*50 + x + c];
    psq[idx] = s;
}

// ===================== shifted-tap MFMA GEMM: D = sqrt(psq + wsq - 2*W.X) =====================
// 9 shifts x (CP/32) K-chunks; B-frags are contiguous 16B channel-last loads (no LDS, no gather).
// 6 bf16-split products per chunk: order per acc = hh, mh, lh, hm, mm, hl.
__global__ __launch_bounds__(256, 2) void k_gemm_mfma(
        const ushort* __restrict__ Wh, const ushort* __restrict__ Wm, const ushort* __restrict__ Wl,
        const ushort* __restrict__ Xh, const ushort* __restrict__ Xm, const ushort* __restrict__ Xl,
        const int* __restrict__ ymapC, const int* __restrict__ omap,
        const float* __restrict__ psq, const float* __restrict__ wsq, float* __restrict__ Dout,
        int M, int CP, int ROWW, int Nper, int NT) {
    int tid = threadIdx.x;
    int n0 = blockIdx.x*192; if (n0 + 192 > NT) n0 = NT - 192;  // overlap: duplicate identical writes
    int m0 = blockIdx.y*128; if (m0 + 128 > M)  m0 = M - 128;
    int lane = tid & 63, wid = tid >> 6;
    int wy = wid >> 1, wx = wid & 1;
    int quad = lane >> 4, ln = lane & 15;

    int aoff[4];
    #pragma unroll
    for (int mt = 0; mt < 4; ++mt)
        aoff[mt] = (m0 + wy*64 + mt*16 + ln)*CP + quad*8;
    int ynq[6];
    #pragma unroll
    for (int nt = 0; nt < 6; ++nt)
        ynq[nt] = ymapC[n0 + wx*96 + nt*16 + ln] + quad*8;

    f32x4 acc[4][6];
    #pragma unroll
    for (int mt = 0; mt < 4; ++mt)
        #pragma unroll
        for (int nt = 0; nt < 6; ++nt) acc[mt][nt] = (f32x4){0.f, 0.f, 0.f, 0.f};

    int MC = M*CP;
    for (int r = 0; r < 3; ++r)
    for (int s = 0; s < 3; ++s) {
        int soffA = (r*3 + s)*MC;
        int soffB = (r*ROWW + s)*CP;
        for (int c0 = 0; c0 < CP; c0 += 32) {
            bf16x8 af0[4], af1[4], af2[4];
            #pragma unroll
            for (int mt = 0; mt < 4; ++mt) {
                int ao = soffA + aoff[mt] + c0;
                af0[mt] = *(const bf16x8*)(Wh + ao);
                af1[mt] = *(const bf16x8*)(Wm + ao);
                af2[mt] = *(const bf16x8*)(Wl + ao);
            }
            bf16x8 bf[6];
            #pragma unroll
            for (int nt = 0; nt < 6; ++nt)
                bf[nt] = *(const bf16x8*)(Xh + soffB + ynq[nt] + c0);
            #pragma unroll
            for (int mt = 0; mt < 4; ++mt)
                #pragma unroll
                for (int nt = 0; nt < 6; ++nt)
                    acc[mt][nt] = __builtin_amdgcn_mfma_f32_16x16x32_bf16(af0[mt], bf[nt], acc[mt][nt], 0, 0, 0);
            #pragma unroll
            for (int mt = 0; mt < 4; ++mt)
                #pragma unroll
                for (int nt = 0; nt < 6; ++nt)
                    acc[mt][nt] = __builtin_amdgcn_mfma_f32_16x16x32_bf16(af1[mt], bf[nt], acc[mt][nt], 0, 0, 0);
            #pragma unroll
            for (int mt = 0; mt < 4; ++mt)
                #pragma unroll
                for (int nt = 0; nt < 6; ++nt)
                    acc[mt][nt] = __builtin_amdgcn_mfma_f32_16x16x32_bf16(af2[mt], bf[nt], acc[mt][nt], 0, 0, 0);
            #pragma unroll
            for (int nt = 0; nt < 6; ++nt)
                bf[nt] = *(const bf16x8*)(Xm + soffB + ynq[nt] + c0);
            #pragma unroll
            for (int mt = 0; mt < 4; ++mt)
                #pragma unroll
                for (int nt = 0; nt < 6; ++nt)
                    acc[mt][nt] = __builtin_amdgcn_mfma_f32_16x16x32_bf16(af0[mt], bf[nt], acc[mt][nt], 0, 0, 0);
            #pragma unroll
            for (int mt = 0; mt < 4; ++mt)
                #pragma unroll
                for (int nt = 0; nt < 6; ++nt)
                    acc[mt][nt] = __builtin_amdgcn_mfma_f32_16x16x32_bf16(af1[mt], bf[nt], acc[mt][nt], 0, 0, 0);
            #pragma unroll
            for (int nt = 0; nt < 6; ++nt)
                bf[nt] = *(const bf16x8*)(Xl + soffB + ynq[nt] + c0);
            #pragma unroll
            for (int mt = 0; mt < 4; ++mt)
                #pragma unroll
                for (int nt = 0; nt < 6; ++nt)
                    acc[mt][nt] = __builtin_amdgcn_mfma_f32_16x16x32_bf16(af0[mt], bf[nt], acc[mt][nt], 0, 0, 0);
        }
    }

    // epilogue: C/D layout col=lane&15, row=quad*4+reg
    #pragma unroll
    for (int mt = 0; mt < 4; ++mt) {
        int gmb = m0 + wy*64 + mt*16 + (quad << 2);
        float4 w4 = *(const float4*)&wsq[gmb];
        #pragma unroll
        for (int nt = 0; nt < 6; ++nt) {
            int gn = n0 + wx*96 + nt*16 + ln;
            float ps = psq[gn];
            size_t ob = (size_t)omap[gn];
            f32x4 a = acc[mt][nt];
            Dout[ob + (size_t)(gmb+0)*Nper] = sqrtf(fmaxf(ps + w4.x - 2.0f*a.x, 0.f));
            Dout[ob + (size_t)(gmb+1)*Nper] = sqrtf(fmaxf(ps + w4.y - 2.0f*a.y, 0.f));
            Dout[ob + (size_t)(gmb+2)*Nper] = sqrtf(fmaxf(ps + w4.z - 2.0f*a.z, 0.f));
            Dout[ob + (size_t)(gmb+3)*Nper] = sqrtf(fmaxf(ps + w4.w - 2.0f*a.w, 0.f));
        }
    }
}

// ===================== triangle + sfm(2,2) after conv1 -> channel-last X2' splits =====================
__global__ void k_tri_sfm2(const float* __restrict__ D1, const float* __restrict__ thr2,
                           const float* __restrict__ w2, ushort* __restrict__ XH,
                           ushort* __restrict__ XM, ushort* __restrict__ XL) {
    int idx = blockIdx.x*256 + threadIdx.x;   // 32*576*32 = 589,824
    int oct = idx & 31;
    int rest = idx >> 5;                      // b*576 + q
    int q = rest % P2, b = rest / P2;
    int i = q / 24, j = q % 24;
    float thr = thr2[b], invw = 1.0f / w2[0];
    int base = (2*i)*48 + 2*j;
    ushort h[8], m[8], l[8];
    #pragma unroll
    for (int j8 = 0; j8 < 8; ++j8) {
        int c = oct*8 + j8;
        float v = 0.f;
        if (c < M1) {
            const float* src = D1 + ((size_t)b*M1 + c)*P1;
            float d00 = src[base], d01 = src[base+1], d10 = src[base+48], d11 = src[base+49];
            float t00 = d00 > thr ? 0.f : 1.f - d00*invw;
            float t01 = d01 > thr ? 0.f : 1.f - d01*invw;
            float t10 = d10 > thr ? 0.f : 1.f - d10*invw;
            float t11 = d11 > thr ? 0.f : 1.f - d11*invw;
            v = 0.25f*(0.9f*t00 + 0.93f*t01 + 0.96f*t10 + 0.99f*t11);
        }
        split3(v, h[j8], m[j8], l[j8]);
    }
    size_t ob = (size_t)rest * C2P + oct*8;
    uint4 ph, pm, pl;
    ph.x = (uint)h[0] | ((uint)h[1]<<16); ph.y = (uint)h[2] | ((uint)h[3]<<16);
    ph.z = (uint)h[4] | ((uint)h[5]<<16); ph.w = (uint)h[6] | ((uint)h[7]<<16);
    pm.x = (uint)m[0] | ((uint)m[1]<<16); pm.y = (uint)m[2] | ((uint)m[3]<<16);
    pm.z = (uint)m[4] | ((uint)m[5]<<16); pm.w = (uint)m[6] | ((uint)m[7]<<16);
    pl.x = (uint)l[0] | ((uint)l[1]<<16); pl.y = (uint)l[2] | ((uint)l[3]<<16);
    pl.z = (uint)l[4] | ((uint)l[5]<<16); pl.w = (uint)l[6] | ((uint)l[7]<<16);
    *(uint4*)&XH[ob] = ph; *(uint4*)&XM[ob] = pm; *(uint4*)&XL[ob] = pl;
}

__global__ void k_z2(const ushort* __restrict__ XH, const ushort* __restrict__ XM,
                     const ushort* __restrict__ XL, float* __restrict__ Z2) {
    int idx = blockIdx.x*256 + threadIdx.x;
    if (idx >= NB*P2) return;
    size_t base = (size_t)idx * C2P;
    float s = 0.f;
    for (int oct = 0; oct < 32; ++oct) {
        uint4 ph = *(const uint4*)&XH[base + oct*8];
        uint4 pm = *(const uint4*)&XM[base + oct*8];
        uint4 pl = *(const uint4*)&XL[base + oct*8];
        const uint* hu = (const uint*)&ph; const uint* mu = (const uint*)&pm;
        const uint* lu = (const uint*)&pl;
        #pragma unroll
        for (int w = 0; w < 4; ++w) {
            float v0 = bf16_f32((ushort)(hu[w] & 0xFFFF)) + bf16_f32((ushort)(mu[w] & 0xFFFF))
                     + bf16_f32((ushort)(lu[w] & 0xFFFF));
            float v1 = bf16_f32((ushort)(hu[w] >> 16)) + bf16_f32((ushort)(mu[w] >> 16))
                     + bf16_f32((ushort)(lu[w] >> 16));
            s += v0*v0 + v1*v1;
        }
    }
    Z2[idx] = s;
}

__global__ void k_psq2(const float* __restrict__ Z2, float* __restrict__ psq) {
    int idx = blockIdx.x*256 + threadIdx.x;
    if (idx >= NB*N2) return;
    int b = idx / N2, p = idx % N2;
    int y = p / 22, x = p % 22;
    const float* zb = Z2 + (size_t)b*P2;
    float s = 0.f;
    #pragma unroll
    for (int r = 0; r < 3; ++r)
        #pragma unroll
        for (int c = 0; c < 3; ++c) s += zb[(y+r)*24 + x + c];
    psq[idx] = s;
}

// ===================== triangle + FC =====================
__global__ void k_fc(const float* __restrict__ D2, const float* __restrict__ fcw,
                     const float* __restrict__ thr3, const float* __restrict__ w3,
                     float* __restrict__ out) {
    int tid = threadIdx.x, b = blockIdx.y;
    float thr = thr3[b];
    float invw = 1.0f / w3[0];
    const float* db = D2 + (size_t)b*FCN;
    float acc[10];
    #pragma unroll
    for (int o = 0; o < 10; ++o) acc[o] = 0.f;
    int base = blockIdx.x*2048;
    #pragma unroll
    for (int it = 0; it < 8; ++it) {
        int p = base + it*256 + tid;
        if (p < FCN) {
            float v = db[p];
            float tv = v > thr ? 0.f : 1.f - v*invw;
            #pragma unroll
            for (int o = 0; o < 10; ++o) acc[o] += tv * fcw[(size_t)o*FCN + p];
        }
    }
    #pragma unroll
    for (int o = 0; o < 10; ++o)
        #pragma unroll
        for (int off = 32; off; off >>= 1) acc[o] += __shfl_down(acc[o], off);
    __shared__ float red[4][10];
    int lane = tid & 63, wid = tid >> 6;
    if (lane == 0) {
        #pragma unroll
        for (int o = 0; o < 10; ++o) red[wid][o] = acc[o];
    }
    __syncthreads();
    if (tid < 10) {
        float s = red[0][tid] + red[1][tid] + red[2][tid] + red[3][tid];
        atomicAdd(&out[b*10 + tid], s);
    }
}

// ===================== launch =====================
extern "C" void kernel_launch(void* const* d_in, const int* in_sizes, int n_in,
                              void* d_out, int out_size, void* d_ws, size_t ws_size,
                              hipStream_t stream) {
    const float* x    = (const float*)d_in[0];
    const float* rgbw = (const float*)d_in[1];
    const float* gryw = (const float*)d_in[2];
    const float* c1w  = (const float*)d_in[3];
    const float* c2w  = (const float*)d_in[4];
    const float* fcw  = (const float*)d_in[5];
    const float* fcb  = (const float*)d_in[6];
    const float* w1   = (const float*)d_in[7];
    const float* w2   = (const float*)d_in[8];
    const float* w3   = (const float*)d_in[9];
    float* out = (float*)d_out;
    float* ws  = (float*)d_ws;

    float* Drgb  = ws + O_A;
    float* Dgray = ws + O_B;
    uint*  hist  = (uint*)(ws + O_HIST);
    uint2* state = (uint2*)(ws + O_STATE);
    float* thr   = ws + O_THR;

    // init threads: 65536 + 73728 + 15488 + 320 + 128 = 155,200 -> 607 blocks
    k_tables<<<607, 256, 0, stream>>>(ws, fcb, out);
    k_wsq<<<M1 + M2, 64, 0, stream>>>(c1w, c2w, ws);
    k_rgb_d<<<dim3(36, 32), 256, 0, stream>>>(x, rgbw, Drgb);
    k_gray_d<<<dim3(36, 32), 256, 0, stream>>>(x, gryw, Dgray);

    auto sel = [&](const float* dptr, int perBatch, uint2* st, float* thro, const float* wc) {
        const int shifts[3] = {21, 10, 0};
        const uint masks[3] = {0u, 0xFFE00000u, 0xFFFFFC00u};
        for (int p = 0; p < 3; ++p) {
            k_hist<<<dim3(32, 32), 256, 0, stream>>>(dptr, perBatch, hist, st, shifts[p], masks[p]);
            k_scan<<<32, 256, 0, stream>>>(hist, st, shifts[p], p == 2, thro, wc);
        }
    };

    sel(Drgb, ORGB*L1N, state + 0,  thr + 0,  w1);
    sel(Dgray, OGRAY*L1N, state + 32, thr + 32, w1);

    k_tri_sfm1<<<5000, 256, 0, stream>>>(Drgb, Dgray, thr + 0, thr + 32, w1,
        (ushort*)(ws + O_X1H), (ushort*)(ws + O_X1M), (ushort*)(ws + O_X1L));
    // W splits overlay the (now dead) Dgray region: 259,200 + 1,440,000 threads -> 6638 blocks
    k_splitw<<<6638, 256, 0, stream>>>(c1w, c2w, ws);
    k_z1<<<313, 256, 0, stream>>>((const ushort*)(ws + O_X1H), (const ushort*)(ws + O_X1M),
        (const ushort*)(ws + O_X1L), ws + O_ZP1);
    k_psq1<<<288, 256, 0, stream>>>(ws + O_ZP1, ws + O_PSQ1);

    float* D1 = ws + O_A;
    k_gemm_mfma<<<dim3(NT1/192, 2), 256, 0, stream>>>(
        (const ushort*)(ws + O_W1H), (const ushort*)(ws + O_W1M), (const ushort*)(ws + O_W1L),
        (const ushort*)(ws + O_X1H), (const ushort*)(ws + O_X1M), (const ushort*)(ws + O_X1L),
        (const int*)(ws + O_YMC1), (const int*)(ws + O_OMAP1),
        ws + O_PSQ1, ws + O_WSQ1, D1, M1, C1P, 50, P1, NT1);

    sel(D1, M1*P1, state + 64, thr + 64, w2);

    k_tri_sfm2<<<2304, 256, 0, stream>>>(D1, thr + 64, w2,
        (ushort*)(ws + O_X2H), (ushort*)(ws + O_X2M), (ushort*)(ws + O_X2L));
    k_z2<<<72, 256, 0, stream>>>((const ushort*)(ws + O_X2H), (const ushort*)(ws + O_X2M),
        (const ushort*)(ws + O_X2L), ws + O_Z2);
    k_psq2<<<61, 256, 0, stream>>>(ws + O_Z2, ws + O_PSQ2);

    float* D2 = ws + O_A;
    k_gemm_mfma<<<dim3((NT2 + 191)/192, 5), 256, 0, stream>>>(
        (const ushort*)(ws + O_W2H), (const ushort*)(ws + O_W2M), (const ushort*)(ws + O_W2L),
        (const ushort*)(ws + O_X2H), (const ushort*)(ws + O_X2M), (const ushort*)(ws + O_X2L),
        (const int*)(ws + O_YMC2), (const int*)(ws + O_OMAP2),
        ws + O_PSQ2, ws + O_WSQ2, D2, M2, C2P, 24, N2, NT2);

    sel(D2, FCN, state + 96, thr + 96, w3);

    k_fc<<<dim3(148, 32), 256, 0, stream>>>(D2, fcw, thr + 96, w3, out);
}

// Round 8
// 1563.461 us; speedup vs baseline: 1.0032x; 1.0032x over previous
//
#include <hip/hip_runtime.h>

typedef unsigned int uint;
typedef unsigned short ushort;

#define NB 32

// geometry
#define L1N 9216      // 96*96
#define ORGB 75
#define OGRAY 25
#define C1 100
#define C1P 128       // channel pad, layer-1 GEMM
#define PLANE1 2500   // 50*50 padded
#define P1 2304       // 48*48
#define M1 225
#define P2 576        // 24*24
#define M2 625
#define C2P 256       // channel pad, layer-2 GEMM (M1=225 -> 256)
#define N2 484        // 22*22
#define FCN 302500    // 625*484
#define NT1 73728     // 2304*32 merged columns
#define NT2 15488     // 484*32 merged columns

// exact ranks: ceil(percent*N) evaluated in fp64
#define KK0 345600u
#define KK1 115200u
#define KK2 207360u
#define KK3 121000u

// ---- workspace layout (float-element offsets) ----
constexpr size_t O_A     = 0;                       // Drgb 22,118,400 -> D1 16.6M -> D2 9.68M
constexpr size_t O_B     = 22118400;                // Dgray 7,372,800 ; W overlays after tri_sfm1
constexpr size_t O_W1H   = O_B;                     // 9*225*128 ushorts = 129,600 floats each
constexpr size_t O_W1M   = O_B + 129600;
constexpr size_t O_W1L   = O_B + 259200;
constexpr size_t O_W2H   = O_B + 388800;            // 9*625*256 ushorts = 720,000 floats each
constexpr size_t O_W2M   = O_B + 1108800;
constexpr size_t O_W2L   = O_B + 1828800;           // end 2,548,800 <= 7,372,800
constexpr size_t O_X     = 29491200;                // X' channel-last split planes
constexpr size_t O_X1H   = O_X;                     // 32*2500*128 ushorts = 5,120,000 floats each
constexpr size_t O_X1M   = O_X + 5120000;
constexpr size_t O_X1L   = O_X + 10240000;
constexpr size_t O_X2H   = O_X;                     // overlay: 32*576*256 ushorts = 2,359,296 floats
constexpr size_t O_X2M   = O_X + 2359296;
constexpr size_t O_X2L   = O_X + 4718592;
constexpr size_t O_HIST  = O_X + 15360000;          // 44,851,200 ; 65,536 uints
constexpr size_t O_STATE = O_HIST + 65536;          // 128 uint2
constexpr size_t O_THR   = O_STATE + 256;
constexpr size_t O_WSQ1  = O_THR + 128;
constexpr size_t O_WSQ2  = O_WSQ1 + 256;
constexpr size_t O_YMC1  = O_WSQ2 + 640;            // 73,728 ints (pre-scaled by C1P, batch-folded)
constexpr size_t O_OMAP1 = O_YMC1 + 73728;
constexpr size_t O_YMC2  = O_OMAP1 + 73728;         // 15,488
constexpr size_t O_OMAP2 = O_YMC2 + 15488;
constexpr size_t O_ZP1   = O_OMAP2 + 15488;         // 80,000
constexpr size_t O_PSQ1  = O_ZP1 + 80000;           // 73,728
constexpr size_t O_Z2    = O_PSQ1 + 73728;          // 18,432
constexpr size_t O_PSQ2  = O_Z2 + 18432;            // 15,488
constexpr size_t O_END   = O_PSQ2 + 15488;          // 45,284,096 floats = 181.1 MB

// ---- bf16 helpers (RNE) ----
__device__ __forceinline__ ushort bf16_rne(float x) {
    uint u = __float_as_uint(x);
    uint r = u + 0x7FFFu + ((u >> 16) & 1u);
    return (ushort)(r >> 16);
}
__device__ __forceinline__ float bf16_f32(ushort h) {
    return __uint_as_float(((uint)h) << 16);
}
__device__ __forceinline__ void split3(float v, ushort& h, ushort& m, ushort& l) {
    h = bf16_rne(v);           float hf = bf16_f32(h);
    m = bf16_rne(v - hf);      float mf = bf16_f32(m);
    l = bf16_rne(v - hf - mf);
}

typedef __attribute__((ext_vector_type(8))) short bf16x8;
typedef __attribute__((ext_vector_type(4))) float f32x4;

// ===================== init: zero hist, states, tables, out=bias =====================
__global__ void k_tables(float* ws, const float* fcb, float* out) {
    int i = blockIdx.x*256 + threadIdx.x;
    if (i < 65536) { ((uint*)(ws + O_HIST))[i] = 0u; return; }
    i -= 65536;
    if (i < NT1) {
        int b = i / P1, p = i % P1;
        ((int*)(ws + O_YMC1))[i]  = (b*PLANE1 + (p/48)*50 + (p%48)) * C1P;
        ((int*)(ws + O_OMAP1))[i] = b*(M1*P1) + p;
        return;
    }
    i -= NT1;
    if (i < NT2) {
        int b = i / N2, p = i % N2;
        ((int*)(ws + O_YMC2))[i]  = (b*P2 + (p/22)*24 + (p%22)) * C2P;
        ((int*)(ws + O_OMAP2))[i] = b*FCN + p;
        return;
    }
    i -= NT2;
    if (i < 320) { out[i] = fcb[i % 10]; return; }
    i -= 320;
    if (i < 128) {
        const uint kks[4] = {KK0, KK1, KK2, KK3};
        ((uint2*)(ws + O_STATE))[i] = make_uint2(0u, kks[i >> 5]);
    }
}

// ===================== per-row squared norms of conv weights =====================
__global__ void k_wsq(const float* c1w, const float* c2w, float* ws) {
    int o = blockIdx.x, lane = threadIdx.x;   // 64 threads
    const float* row; int K; float* dst;
    if (o < M1) { row = c1w + (size_t)o*900; K = 900; dst = ws + O_WSQ1 + o; }
    else { int oo = o - M1; row = c2w + (size_t)oo*2025; K = 2025; dst = ws + O_WSQ2 + oo; }
    float s = 0.f;
    for (int k = lane; k < K; k += 64) { float v = row[k]; s += v*v; }
    #pragma unroll
    for (int off = 32; off; off >>= 1) s += __shfl_down(s, off);
    if (lane == 0) *dst = s;
}

// ===================== split W into tap-major bf16 planes Wrs[9][M][C'] =====================
__global__ void k_splitw(const float* __restrict__ c1w, const float* __restrict__ c2w,
                         float* __restrict__ ws) {
    int i = blockIdx.x*256 + threadIdx.x;
    ushort h, m, l;
    if (i < 9*M1*C1P) {
        int rs = i / (M1*C1P), r2 = i % (M1*C1P);
        int mm = r2 / C1P, c = r2 % C1P;
        float x = (c < C1) ? c1w[(size_t)mm*900 + c*9 + rs] : 0.f;
        split3(x, h, m, l);
        ((ushort*)(ws + O_W1H))[i] = h;
        ((ushort*)(ws + O_W1M))[i] = m;
        ((ushort*)(ws + O_W1L))[i] = l;
        return;
    }
    i -= 9*M1*C1P;
    if (i < 9*M2*C2P) {
        int rs = i / (M2*C2P), r2 = i % (M2*C2P);
        int mm = r2 / C2P, c = r2 % C2P;
        float x = (c < M1) ? c2w[(size_t)mm*2025 + c*9 + rs] : 0.f;
        split3(x, h, m, l);
        ((ushort*)(ws + O_W2H))[i] = h;
        ((ushort*)(ws + O_W2M))[i] = m;
        ((ushort*)(ws + O_W2L))[i] = l;
    }
}

// ===================== stage 1: rgb distance =====================
__global__ void k_rgb_d(const float* __restrict__ x, const float* __restrict__ rgbw,
                        float* __restrict__ D) {
    __shared__ float lw[ORGB*3];
    __shared__ float lwsq[ORGB];
    int tid = threadIdx.x;
    if (tid < ORGB*3) lw[tid] = rgbw[tid];
    __syncthreads();
    if (tid < ORGB) {
        float a = lw[tid*3], b = lw[tid*3+1], c = lw[tid*3+2];
        lwsq[tid] = 25.0f*(a*a + b*b + c*c);
    }
    __syncthreads();
    int p = blockIdx.x*256 + tid;
    int b = blockIdx.y;
    int y = p / 96, xx = p % 96;
    const float* xb = x + (size_t)b*3*10000;
    float s1_0 = 0, s1_1 = 0, s1_2 = 0, s2 = 0;
    #pragma unroll
    for (int r = 0; r < 5; ++r)
        #pragma unroll
        for (int s = 0; s < 5; ++s) {
            int off = (y+r)*100 + (xx+s);
            float v0 = xb[off], v1 = xb[10000+off], v2 = xb[20000+off];
            s1_0 += v0; s1_1 += v1; s1_2 += v2;
            s2 += v0*v0 + v1*v1 + v2*v2;
        }
    float* Db = D + (size_t)b*ORGB*L1N + p;
    for (int o = 0; o < ORGB; ++o) {
        float dot = lw[o*3]*s1_0 + lw[o*3+1]*s1_1 + lw[o*3+2]*s1_2;
        float d2 = s2 + lwsq[o] - 2.0f*dot;
        Db[(size_t)o*L1N] = sqrtf(fmaxf(d2, 0.0f));
    }
}

// ===================== stage 1: gray distance =====================
__global__ void k_gray_d(const float* __restrict__ x, const float* __restrict__ gw,
                         float* __restrict__ D) {
    __shared__ float lw[625];
    __shared__ float lwsq[25];
    int tid = threadIdx.x;
    for (int i = tid; i < 625; i += 256) lw[i] = gw[i];
    __syncthreads();
    if (tid < 25) {
        float s = 0.f;
        for (int k = 0; k < 25; ++k) { float v = lw[tid*25+k]; s += v*v; }
        lwsq[tid] = s;
    }
    __syncthreads();
    int p = blockIdx.x*256 + tid;
    int b = blockIdx.y;
    int y = p / 96, xx = p % 96;
    const float* xb = x + (size_t)b*3*10000;
    float pv[25]; float psum = 0.f;
    #pragma unroll
    for (int r = 0; r < 5; ++r)
        #pragma unroll
        for (int s = 0; s < 5; ++s) {
            int off = (y+r)*100 + (xx+s);
            float g = 0.2989f*xb[off] + 0.587f*xb[10000+off] + 0.114f*xb[20000+off];
            pv[r*5+s] = g; psum += g*g;
        }
    float* Db = D + (size_t)b*OGRAY*L1N + p;
    for (int o = 0; o < 25; ++o) {
        float dot = 0.f;
        #pragma unroll
        for (int k = 0; k < 25; ++k) dot += lw[o*25+k]*pv[k];
        float d2 = psum + lwsq[o] - 2.0f*dot;
        Db[(size_t)o*L1N] = sqrtf(fmaxf(d2, 0.0f));
    }
}

// ===================== exact rank selection: histogram pass =====================
__global__ void k_hist(const float* __restrict__ d, int perBatch, uint* __restrict__ hist,
                       const uint2* __restrict__ state, int shift, uint pmask) {
    __shared__ uint lh[2048];
    int tid = threadIdx.x;
    for (int i = tid; i < 2048; i += 256) lh[i] = 0u;
    __syncthreads();
    int b = blockIdx.y;
    uint pref = state[b].x;
    const float* db = d + (size_t)b*perBatch;
    for (int i = blockIdx.x*256 + tid; i < perBatch; i += 256*32) {
        uint bits = __float_as_uint(db[i]);
        if ((bits & pmask) == pref)
            atomicAdd(&lh[(bits >> shift) & 2047u], 1u);
    }
    __syncthreads();
    uint* hb = hist + (size_t)b*2048;
    for (int i = tid; i < 2048; i += 256) {
        uint v = lh[i];
        if (v) atomicAdd(&hb[i], v);
    }
}

// ===================== selection: scan + state update (+zero hist) =====================
__global__ void k_scan(uint* __restrict__ hist, uint2* __restrict__ state, int shift,
                       int isFinal, float* __restrict__ thr_out, const float* __restrict__ wcap) {
    __shared__ uint ss[256];
    int b = blockIdx.x, t = threadIdx.x;
    uint* hb = hist + (size_t)b*2048;
    uint bins[8]; uint seg = 0;
    #pragma unroll
    for (int i = 0; i < 8; ++i) { bins[i] = hb[t*8+i]; seg += bins[i]; }
    ss[t] = seg;
    __syncthreads();
    for (int off = 1; off < 256; off <<= 1) {
        uint add = (t >= off) ? ss[t-off] : 0u;
        __syncthreads();
        ss[t] += add;
        __syncthreads();
    }
    uint incl = ss[t], excl = incl - seg;
    uint rank = state[b].y;
    if (excl < rank && rank <= incl) {
        uint c = excl;
        #pragma unroll
        for (int i = 0; i < 8; ++i) {
            c += bins[i];
            if (c >= rank) {
                uint bin = (uint)(t*8+i);
                uint pref = state[b].x | (bin << shift);
                if (isFinal) {
                    thr_out[b] = fminf(__uint_as_float(pref), wcap[0]);
                } else {
                    state[b] = make_uint2(pref, rank - (c - bins[i]));
                }
                break;
            }
        }
    }
    __syncthreads();
    #pragma unroll
    for (int i = 0; i < 8; ++i) hb[t*8+i] = 0u;
}

// ===================== triangle + concat + sfm(2,2) -> channel-last X1' splits =====================
__global__ void k_tri_sfm1(const float* __restrict__ Drgb, const float* __restrict__ Dgray,
                           const float* __restrict__ thrA, const float* __restrict__ thrB,
                           const float* __restrict__ w1, ushort* __restrict__ XH,
                           ushort* __restrict__ XM, ushort* __restrict__ XL) {
    int idx = blockIdx.x*256 + threadIdx.x;   // 32*2500*16 = 1,280,000
    int oct = idx & 15;
    int rest = idx >> 4;                      // b*2500 + q
    int q = rest % PLANE1, b = rest / PLANE1;
    int pi = q / 50, pj = q % 50;
    bool border = (pi == 0 || pi == 49 || pj == 0 || pj == 49);
    float invw = 1.0f / w1[0];
    float tA = thrA[b], tB = thrB[b];
    int base = (2*(pi-1))*96 + 2*(pj-1);
    ushort h[8], m[8], l[8];
    #pragma unroll
    for (int j8 = 0; j8 < 8; ++j8) {
        int c = oct*8 + j8;
        float v = 0.f;
        if (!border && c < C1) {
            const float* src; float thr;
            if (c < ORGB) { src = Drgb + ((size_t)b*ORGB + c)*L1N; thr = tA; }
            else          { src = Dgray + ((size_t)b*OGRAY + (c-ORGB))*L1N; thr = tB; }
            float d00 = src[base], d01 = src[base+1], d10 = src[base+96], d11 = src[base+97];
            float t00 = d00 > thr ? 0.f : 1.f - d00*invw;
            float t01 = d01 > thr ? 0.f : 1.f - d01*invw;
            float t10 = d10 > thr ? 0.f : 1.f - d10*invw;
            float t11 = d11 > thr ? 0.f : 1.f - d11*invw;
            v = 0.25f*(0.9f*t00 + 0.93f*t01 + 0.96f*t10 + 0.99f*t11);
        }
        split3(v, h[j8], m[j8], l[j8]);
    }
    size_t ob = (size_t)rest * C1P + oct*8;
    uint4 ph, pm, pl;
    ph.x = (uint)h[0] | ((uint)h[1]<<16); ph.y = (uint)h[2] | ((uint)h[3]<<16);
    ph.z = (uint)h[4] | ((uint)h[5]<<16); ph.w = (uint)h[6] | ((uint)h[7]<<16);
    pm.x = (uint)m[0] | ((uint)m[1]<<16); pm.y = (uint)m[2] | ((uint)m[3]<<16);
    pm.z = (uint)m[4] | ((uint)m[5]<<16); pm.w = (uint)m[6] | ((uint)m[7]<<16);
    pl.x = (uint)l[0] | ((uint)l[1]<<16); pl.y = (uint)l[2] | ((uint)l[3]<<16);
    pl.z = (uint)l[4] | ((uint)l[5]<<16); pl.w = (uint)l[6] | ((uint)l[7]<<16);
    *(uint4*)&XH[ob] = ph; *(uint4*)&XM[ob] = pm; *(uint4*)&XL[ob] = pl;
}

// ===================== channel-sum of squares (padded plane, channel-last) =====================
__global__ void k_z1(const ushort* __restrict__ XH, const ushort* __restrict__ XM,
                     const ushort* __restrict__ XL, float* __restrict__ Zp) {
    int idx = blockIdx.x*256 + threadIdx.x;
    if (idx >= NB*PLANE1) return;
    size_t base = (size_t)idx * C1P;
    float s = 0.f;
    for (int oct = 0; oct < 16; ++oct) {
        uint4 ph = *(const uint4*)&XH[base + oct*8];
        uint4 pm = *(const uint4*)&XM[base + oct*8];
        uint4 pl = *(const uint4*)&XL[base + oct*8];
        const uint* hu = (const uint*)&ph; const uint* mu = (const uint*)&pm;
        const uint* lu = (const uint*)&pl;
        #pragma unroll
        for (int w = 0; w < 4; ++w) {
            float v0 = bf16_f32((ushort)(hu[w] & 0xFFFF)) + bf16_f32((ushort)(mu[w] & 0xFFFF))
                     + bf16_f32((ushort)(lu[w] & 0xFFFF));
            float v1 = bf16_f32((ushort)(hu[w] >> 16)) + bf16_f32((ushort)(mu[w] >> 16))
                     + bf16_f32((ushort)(lu[w] >> 16));
            s += v0*v0 + v1*v1;
        }
    }
    Zp[idx] = s;
}

__global__ void k_psq1(const float* __restrict__ Zp, float* __restrict__ psq) {
    int idx = blockIdx.x*256 + threadIdx.x;   // exactly 32*2304
    int b = idx / P1, p = idx % P1;
    int y = p / 48, x = p % 48;
    const float* zb = Zp + (size_t)b*PLANE1;
    float s = 0.f;
    #pragma unroll
    for (int r = 0; r < 3; ++r)
        #pragma unroll
        for (int c = 0; c < 3; ++c) s += zb[(y+r)*50 + x + c];
    psq[idx] = s;
}

// ===================== shifted-tap MFMA GEMM: D = sqrt(psq + wsq - 2*W.X) =====================
// K-chunk OUTER, 9 taps INNER: the 9 taps of one chunk touch a 3x3-pixel
// neighborhood that stays L1/L2-resident (R7 had taps outer -> 780 MB HBM re-fetch).
// B-frags are contiguous 16B channel-last loads (no LDS, no gather).
// 6 bf16-split products per (chunk, tap): hh, mh, lh, hm, mm, hl.
__global__ __launch_bounds__(256, 2) void k_gemm_mfma(
        const ushort* __restrict__ Wh, const ushort* __restrict__ Wm, const ushort* __restrict__ Wl,
        const ushort* __restrict__ Xh, const ushort* __restrict__ Xm, const ushort* __restrict__ Xl,
        const int* __restrict__ ymapC, const int* __restrict__ omap,
        const float* __restrict__ psq, const float* __restrict__ wsq, float* __restrict__ Dout,
        int M, int CP, int ROWW, int Nper, int NT) {
    int tid = threadIdx.x;
    int n0 = blockIdx.x*192; if (n0 + 192 > NT) n0 = NT - 192;  // overlap: duplicate identical writes
    int m0 = blockIdx.y*128; if (m0 + 128 > M)  m0 = M - 128;
    int lane = tid & 63, wid = tid >> 6;
    int wy = wid >> 1, wx = wid & 1;
    int quad = lane >> 4, ln = lane & 15;

    int aoff[4];
    #pragma unroll
    for (int mt = 0; mt < 4; ++mt)
        aoff[mt] = (m0 + wy*64 + mt*16 + ln)*CP + quad*8;
    int ynq[6];
    #pragma unroll
    for (int nt = 0; nt < 6; ++nt)
        ynq[nt] = ymapC[n0 + wx*96 + nt*16 + ln] + quad*8;

    f32x4 acc[4][6];
    #pragma unroll
    for (int mt = 0; mt < 4; ++mt)
        #pragma unroll
        for (int nt = 0; nt < 6; ++nt) acc[mt][nt] = (f32x4){0.f, 0.f, 0.f, 0.f};

    int MC = M*CP;
    for (int c0 = 0; c0 < CP; c0 += 32) {
        for (int r = 0; r < 3; ++r)
        for (int s = 0; s < 3; ++s) {
            int soffA = (r*3 + s)*MC + c0;
            int soffB = (r*ROWW + s)*CP + c0;
            bf16x8 af0[4], af1[4], af2[4];
            #pragma unroll
            for (int mt = 0; mt < 4; ++mt) {
                int ao = soffA + aoff[mt];
                af0[mt] = *(const bf16x8*)(Wh + ao);
                af1[mt] = *(const bf16x8*)(Wm + ao);
                af2[mt] = *(const bf16x8*)(Wl + ao);
            }
            bf16x8 bf[6];
            #pragma unroll
            for (int nt = 0; nt < 6; ++nt)
                bf[nt] = *(const bf16x8*)(Xh + soffB + ynq[nt]);
            #pragma unroll
            for (int mt = 0; mt < 4; ++mt)
                #pragma unroll
                for (int nt = 0; nt < 6; ++nt)
                    acc[mt][nt] = __builtin_amdgcn_mfma_f32_16x16x32_bf16(af0[mt], bf[nt], acc[mt][nt], 0, 0, 0);
            #pragma unroll
            for (int mt = 0; mt < 4; ++mt)
                #pragma unroll
                for (int nt = 0; nt < 6; ++nt)
                    acc[mt][nt] = __builtin_amdgcn_mfma_f32_16x16x32_bf16(af1[mt], bf[nt], acc[mt][nt], 0, 0, 0);
            #pragma unroll
            for (int mt = 0; mt < 4; ++mt)
                #pragma unroll
                for (int nt = 0; nt < 6; ++nt)
                    acc[mt][nt] = __builtin_amdgcn_mfma_f32_16x16x32_bf16(af2[mt], bf[nt], acc[mt][nt], 0, 0, 0);
            #pragma unroll
            for (int nt = 0; nt < 6; ++nt)
                bf[nt] = *(const bf16x8*)(Xm + soffB + ynq[nt]);
            #pragma unroll
            for (int mt = 0; mt < 4; ++mt)
                #pragma unroll
                for (int nt = 0; nt < 6; ++nt)
                    acc[mt][nt] = __builtin_amdgcn_mfma_f32_16x16x32_bf16(af0[mt], bf[nt], acc[mt][nt], 0, 0, 0);
            #pragma unroll
            for (int mt = 0; mt < 4; ++mt)
                #pragma unroll
                for (int nt = 0; nt < 6; ++nt)
                    acc[mt][nt] = __builtin_amdgcn_mfma_f32_16x16x32_bf16(af1[mt], bf[nt], acc[mt][nt], 0, 0, 0);
            #pragma unroll
            for (int nt = 0; nt < 6; ++nt)
                bf[nt] = *(const bf16x8*)(Xl + soffB + ynq[nt]);
            #pragma unroll
            for (int mt = 0; mt < 4; ++mt)
                #pragma unroll
                for (int nt = 0; nt < 6; ++nt)
                    acc[mt][nt] = __builtin_amdgcn_mfma_f32_16x16x32_bf16(af0[mt], bf[nt], acc[mt][nt], 0, 0, 0);
        }
    }

    // epilogue: C/D layout col=lane&15, row=quad*4+reg
    #pragma unroll
    for (int mt = 0; mt < 4; ++mt) {
        int gmb = m0 + wy*64 + mt*16 + (quad << 2);
        float4 w4 = *(const float4*)&wsq[gmb];
        #pragma unroll
        for (int nt = 0; nt < 6; ++nt) {
            int gn = n0 + wx*96 + nt*16 + ln;
            float ps = psq[gn];
            size_t ob = (size_t)omap[gn];
            f32x4 a = acc[mt][nt];
            Dout[ob + (size_t)(gmb+0)*Nper] = sqrtf(fmaxf(ps + w4.x - 2.0f*a.x, 0.f));
            Dout[ob + (size_t)(gmb+1)*Nper] = sqrtf(fmaxf(ps + w4.y - 2.0f*a.y, 0.f));
            Dout[ob + (size_t)(gmb+2)*Nper] = sqrtf(fmaxf(ps + w4.z - 2.0f*a.z, 0.f));
            Dout[ob + (size_t)(gmb+3)*Nper] = sqrtf(fmaxf(ps + w4.w - 2.0f*a.w, 0.f));
        }
    }
}

// ===================== triangle + sfm(2,2) after conv1 -> channel-last X2' splits =====================
__global__ void k_tri_sfm2(const float* __restrict__ D1, const float* __restrict__ thr2,
                           const float* __restrict__ w2, ushort* __restrict__ XH,
                           ushort* __restrict__ XM, ushort* __restrict__ XL) {
    int idx = blockIdx.x*256 + threadIdx.x;   // 32*576*32 = 589,824
    int oct = idx & 31;
    int rest = idx >> 5;                      // b*576 + q
    int q = rest % P2, b = rest / P2;
    int i = q / 24, j = q % 24;
    float thr = thr2[b], invw = 1.0f / w2[0];
    int base = (2*i)*48 + 2*j;
    ushort h[8], m[8], l[8];
    #pragma unroll
    for (int j8 = 0; j8 < 8; ++j8) {
        int c = oct*8 + j8;
        float v = 0.f;
        if (c < M1) {
            const float* src = D1 + ((size_t)b*M1 + c)*P1;
            float d00 = src[base], d01 = src[base+1], d10 = src[base+48], d11 = src[base+49];
            float t00 = d00 > thr ? 0.f : 1.f - d00*invw;
            float t01 = d01 > thr ? 0.f : 1.f - d01*invw;
            float t10 = d10 > thr ? 0.f : 1.f - d10*invw;
            float t11 = d11 > thr ? 0.f : 1.f - d11*invw;
            v = 0.25f*(0.9f*t00 + 0.93f*t01 + 0.96f*t10 + 0.99f*t11);
        }
        split3(v, h[j8], m[j8], l[j8]);
    }
    size_t ob = (size_t)rest * C2P + oct*8;
    uint4 ph, pm, pl;
    ph.x = (uint)h[0] | ((uint)h[1]<<16); ph.y = (uint)h[2] | ((uint)h[3]<<16);
    ph.z = (uint)h[4] | ((uint)h[5]<<16); ph.w = (uint)h[6] | ((uint)h[7]<<16);
    pm.x = (uint)m[0] | ((uint)m[1]<<16); pm.y = (uint)m[2] | ((uint)m[3]<<16);
    pm.z = (uint)m[4] | ((uint)m[5]<<16); pm.w = (uint)m[6] | ((uint)m[7]<<16);
    pl.x = (uint)l[0] | ((uint)l[1]<<16); pl.y = (uint)l[2] | ((uint)l[3]<<16);
    pl.z = (uint)l[4] | ((uint)l[5]<<16); pl.w = (uint)l[6] | ((uint)l[7]<<16);
    *(uint4*)&XH[ob] = ph; *(uint4*)&XM[ob] = pm; *(uint4*)&XL[ob] = pl;
}

__global__ void k_z2(const ushort* __restrict__ XH, const ushort* __restrict__ XM,
                     const ushort* __restrict__ XL, float* __restrict__ Z2) {
    int idx = blockIdx.x*256 + threadIdx.x;
    if (idx >= NB*P2) return;
    size_t base = (size_t)idx * C2P;
    float s = 0.f;
    for (int oct = 0; oct < 32; ++oct) {
        uint4 ph = *(const uint4*)&XH[base + oct*8];
        uint4 pm = *(const uint4*)&XM[base + oct*8];
        uint4 pl = *(const uint4*)&XL[base + oct*8];
        const uint* hu = (const uint*)&ph; const uint* mu = (const uint*)&pm;
        const uint* lu = (const uint*)&pl;
        #pragma unroll
        for (int w = 0; w < 4; ++w) {
            float v0 = bf16_f32((ushort)(hu[w] & 0xFFFF)) + bf16_f32((ushort)(mu[w] & 0xFFFF))
                     + bf16_f32((ushort)(lu[w] & 0xFFFF));
            float v1 = bf16_f32((ushort)(hu[w] >> 16)) + bf16_f32((ushort)(mu[w] >> 16))
                     + bf16_f32((ushort)(lu[w] >> 16));
            s += v0*v0 + v1*v1;
        }
    }
    Z2[idx] = s;
}

__global__ void k_psq2(const float* __restrict__ Z2, float* __restrict__ psq) {
    int idx = blockIdx.x*256 + threadIdx.x;
    if (idx >= NB*N2) return;
    int b = idx / N2, p = idx % N2;
    int y = p / 22, x = p % 22;
    const float* zb = Z2 + (size_t)b*P2;
    float s = 0.f;
    #pragma unroll
    for (int r = 0; r < 3; ++r)
        #pragma unroll
        for (int c = 0; c < 3; ++c) s += zb[(y+r)*24 + x + c];
    psq[idx] = s;
}

// ===================== triangle + FC =====================
__global__ void k_fc(const float* __restrict__ D2, const float* __restrict__ fcw,
                     const float* __restrict__ thr3, const float* __restrict__ w3,
                     float* __restrict__ out) {
    int tid = threadIdx.x, b = blockIdx.y;
    float thr = thr3[b];
    float invw = 1.0f / w3[0];
    const float* db = D2 + (size_t)b*FCN;
    float acc[10];
    #pragma unroll
    for (int o = 0; o < 10; ++o) acc[o] = 0.f;
    int base = blockIdx.x*2048;
    #pragma unroll
    for (int it = 0; it < 8; ++it) {
        int p = base + it*256 + tid;
        if (p < FCN) {
            float v = db[p];
            float tv = v > thr ? 0.f : 1.f - v*invw;
            #pragma unroll
            for (int o = 0; o < 10; ++o) acc[o] += tv * fcw[(size_t)o*FCN + p];
        }
    }
    #pragma unroll
    for (int o = 0; o < 10; ++o)
        #pragma unroll
        for (int off = 32; off; off >>= 1) acc[o] += __shfl_down(acc[o], off);
    __shared__ float red[4][10];
    int lane = tid & 63, wid = tid >> 6;
    if (lane == 0) {
        #pragma unroll
        for (int o = 0; o < 10; ++o) red[wid][o] = acc[o];
    }
    __syncthreads();
    if (tid < 10) {
        float s = red[0][tid] + red[1][tid] + red[2][tid] + red[3][tid];
        atomicAdd(&out[b*10 + tid], s);
    }
}

// ===================== launch =====================
extern "C" void kernel_launch(void* const* d_in, const int* in_sizes, int n_in,
                              void* d_out, int out_size, void* d_ws, size_t ws_size,
                              hipStream_t stream) {
    const float* x    = (const float*)d_in[0];
    const float* rgbw = (const float*)d_in[1];
    const float* gryw = (const float*)d_in[2];
    const float* c1w  = (const float*)d_in[3];
    const float* c2w  = (const float*)d_in[4];
    const float* fcw  = (const float*)d_in[5];
    const float* fcb  = (const float*)d_in[6];
    const float* w1   = (const float*)d_in[7];
    const float* w2   = (const float*)d_in[8];
    const float* w3   = (const float*)d_in[9];
    float* out = (float*)d_out;
    float* ws  = (float*)d_ws;

    float* Drgb  = ws + O_A;
    float* Dgray = ws + O_B;
    uint*  hist  = (uint*)(ws + O_HIST);
    uint2* state = (uint2*)(ws + O_STATE);
    float* thr   = ws + O_THR;

    // init threads: 65536 + 73728 + 15488 + 320 + 128 = 155,200 -> 607 blocks
    k_tables<<<607, 256, 0, stream>>>(ws, fcb, out);
    k_wsq<<<M1 + M2, 64, 0, stream>>>(c1w, c2w, ws);
    k_rgb_d<<<dim3(36, 32), 256, 0, stream>>>(x, rgbw, Drgb);
    k_gray_d<<<dim3(36, 32), 256, 0, stream>>>(x, gryw, Dgray);

    auto sel = [&](const float* dptr, int perBatch, uint2* st, float* thro, const float* wc) {
        const int shifts[3] = {21, 10, 0};
        const uint masks[3] = {0u, 0xFFE00000u, 0xFFFFFC00u};
        for (int p = 0; p < 3; ++p) {
            k_hist<<<dim3(32, 32), 256, 0, stream>>>(dptr, perBatch, hist, st, shifts[p], masks[p]);
            k_scan<<<32, 256, 0, stream>>>(hist, st, shifts[p], p == 2, thro, wc);
        }
    };

    sel(Drgb, ORGB*L1N, state + 0,  thr + 0,  w1);
    sel(Dgray, OGRAY*L1N, state + 32, thr + 32, w1);

    k_tri_sfm1<<<5000, 256, 0, stream>>>(Drgb, Dgray, thr + 0, thr + 32, w1,
        (ushort*)(ws + O_X1H), (ushort*)(ws + O_X1M), (ushort*)(ws + O_X1L));
    // W splits overlay the (now dead) Dgray region: 259,200 + 1,440,000 threads -> 6638 blocks
    k_splitw<<<6638, 256, 0, stream>>>(c1w, c2w, ws);
    k_z1<<<313, 256, 0, stream>>>((const ushort*)(ws + O_X1H), (const ushort*)(ws + O_X1M),
        (const ushort*)(ws + O_X1L), ws + O_ZP1);
    k_psq1<<<288, 256, 0, stream>>>(ws + O_ZP1, ws + O_PSQ1);

    float* D1 = ws + O_A;
    k_gemm_mfma<<<dim3(NT1/192, 2), 256, 0, stream>>>(
        (const ushort*)(ws + O_W1H), (const ushort*)(ws + O_W1M), (const ushort*)(ws + O_W1L),
        (const ushort*)(ws + O_X1H), (const ushort*)(ws + O_X1M), (const ushort*)(ws + O_X1L),
        (const int*)(ws + O_YMC1), (const int*)(ws + O_OMAP1),
        ws + O_PSQ1, ws + O_WSQ1, D1, M1, C1P, 50, P1, NT1);

    sel(D1, M1*P1, state + 64, thr + 64, w2);

    k_tri_sfm2<<<2304, 256, 0, stream>>>(D1, thr + 64, w2,
        (ushort*)(ws + O_X2H), (ushort*)(ws + O_X2M), (ushort*)(ws + O_X2L));
    k_z2<<<72, 256, 0, stream>>>((const ushort*)(ws + O_X2H), (const ushort*)(ws + O_X2M),
        (const ushort*)(ws + O_X2L), ws + O_Z2);
    k_psq2<<<61, 256, 0, stream>>>(ws + O_Z2, ws + O_PSQ2);

    float* D2 = ws + O_A;
    k_gemm_mfma<<<dim3((NT2 + 191)/192, 5), 256, 0, stream>>>(
        (const ushort*)(ws + O_W2H), (const ushort*)(ws + O_W2M), (const ushort*)(ws + O_W2L),
        (const ushort*)(ws + O_X2H), (const ushort*)(ws + O_X2M), (const ushort*)(ws + O_X2L),
        (const int*)(ws + O_YMC2), (const int*)(ws + O_OMAP2),
        ws + O_PSQ2, ws + O_WSQ2, D2, M2, C2P, 24, N2, NT2);

    sel(D2, FCN, state + 96, thr + 96, w3);

    k_fc<<<dim3(148, 32), 256, 0, stream>>>(D2, fcw, thr + 96, w3, out);
}

// Round 9
// 1213.788 us; speedup vs baseline: 1.2922x; 1.2881x over previous
//
#include <hip/hip_runtime.h>

typedef unsigned int uint;
typedef unsigned short ushort;

#define NB 32

// geometry
#define L1N 9216      // 96*96
#define ORGB 75
#define OGRAY 25
#define C1 100
#define C1P 128       // channel pad, layer-1 GEMM
#define PLANE1 2500   // 50*50 padded
#define P1 2304       // 48*48
#define M1 225
#define P2 576        // 24*24
#define M2 625
#define C2P 256       // channel pad, layer-2 GEMM (M1=225 -> 256)
#define N2 484        // 22*22
#define FCN 302500    // 625*484
#define NT1 73728     // 2304*32 merged columns
#define NT2 15488     // 484*32 merged columns

// exact ranks: ceil(percent*N) evaluated in fp64
#define KK0 345600u
#define KK1 115200u
#define KK2 207360u
#define KK3 121000u

// ---- workspace layout (float-element offsets) ----
constexpr size_t O_A     = 0;                       // Drgb 22,118,400 -> D1 16.6M -> D2 9.68M
constexpr size_t O_B     = 22118400;                // Dgray 7,372,800 ; W overlays after tri_sfm1
constexpr size_t O_W1H   = O_B;                     // 9*225*128 ushorts = 129,600 floats each
constexpr size_t O_W1M   = O_B + 129600;
constexpr size_t O_W1L   = O_B + 259200;
constexpr size_t O_W2H   = O_B + 388800;            // 9*625*256 ushorts = 720,000 floats each
constexpr size_t O_W2M   = O_B + 1108800;
constexpr size_t O_W2L   = O_B + 1828800;           // end 2,548,800 <= 7,372,800
constexpr size_t O_X     = 29491200;                // X' channel-last split planes
constexpr size_t O_X1H   = O_X;                     // 32*2500*128 ushorts = 5,120,000 floats each
constexpr size_t O_X1M   = O_X + 5120000;
constexpr size_t O_X1L   = O_X + 10240000;
constexpr size_t O_X2H   = O_X;                     // overlay: 32*576*256 ushorts = 2,359,296 floats
constexpr size_t O_X2M   = O_X + 2359296;
constexpr size_t O_X2L   = O_X + 4718592;
constexpr size_t O_HIST  = O_X + 15360000;          // 44,851,200 ; 65,536 uints
constexpr size_t O_STATE = O_HIST + 65536;          // 128 uint2
constexpr size_t O_THR   = O_STATE + 256;
constexpr size_t O_WSQ1  = O_THR + 128;
constexpr size_t O_WSQ2  = O_WSQ1 + 256;
constexpr size_t O_ZP1   = O_WSQ2 + 640;            // 80,000
constexpr size_t O_PSQ1  = O_ZP1 + 80000;           // 73,728
constexpr size_t O_Z2    = O_PSQ1 + 73728;          // 18,432
constexpr size_t O_PSQ2  = O_Z2 + 18432;            // 15,488
constexpr size_t O_END   = O_PSQ2 + 15488;          // ~180.7 MB

// ---- bf16 helpers (RNE) ----
__device__ __forceinline__ ushort bf16_rne(float x) {
    uint u = __float_as_uint(x);
    uint r = u + 0x7FFFu + ((u >> 16) & 1u);
    return (ushort)(r >> 16);
}
__device__ __forceinline__ float bf16_f32(ushort h) {
    return __uint_as_float(((uint)h) << 16);
}
__device__ __forceinline__ void split3(float v, ushort& h, ushort& m, ushort& l) {
    h = bf16_rne(v);           float hf = bf16_f32(h);
    m = bf16_rne(v - hf);      float mf = bf16_f32(m);
    l = bf16_rne(v - hf - mf);
}

typedef __attribute__((ext_vector_type(8))) short bf16x8;
typedef __attribute__((ext_vector_type(4))) float f32x4;

// ===================== init: zero hist, states, out=bias =====================
__global__ void k_tables(float* ws, const float* fcb, float* out) {
    int i = blockIdx.x*256 + threadIdx.x;
    if (i < 65536) { ((uint*)(ws + O_HIST))[i] = 0u; return; }
    i -= 65536;
    if (i < 320) { out[i] = fcb[i % 10]; return; }
    i -= 320;
    if (i < 128) {
        const uint kks[4] = {KK0, KK1, KK2, KK3};
        ((uint2*)(ws + O_STATE))[i] = make_uint2(0u, kks[i >> 5]);
    }
}

// ===================== per-row squared norms of conv weights =====================
__global__ void k_wsq(const float* c1w, const float* c2w, float* ws) {
    int o = blockIdx.x, lane = threadIdx.x;   // 64 threads
    const float* row; int K; float* dst;
    if (o < M1) { row = c1w + (size_t)o*900; K = 900; dst = ws + O_WSQ1 + o; }
    else { int oo = o - M1; row = c2w + (size_t)oo*2025; K = 2025; dst = ws + O_WSQ2 + oo; }
    float s = 0.f;
    for (int k = lane; k < K; k += 64) { float v = row[k]; s += v*v; }
    #pragma unroll
    for (int off = 32; off; off >>= 1) s += __shfl_down(s, off);
    if (lane == 0) *dst = s;
}

// ===================== split W into tap-major bf16 planes Wrs[9][M][C'] =====================
__global__ void k_splitw(const float* __restrict__ c1w, const float* __restrict__ c2w,
                         float* __restrict__ ws) {
    int i = blockIdx.x*256 + threadIdx.x;
    ushort h, m, l;
    if (i < 9*M1*C1P) {
        int rs = i / (M1*C1P), r2 = i % (M1*C1P);
        int mm = r2 / C1P, c = r2 % C1P;
        float x = (c < C1) ? c1w[(size_t)mm*900 + c*9 + rs] : 0.f;
        split3(x, h, m, l);
        ((ushort*)(ws + O_W1H))[i] = h;
        ((ushort*)(ws + O_W1M))[i] = m;
        ((ushort*)(ws + O_W1L))[i] = l;
        return;
    }
    i -= 9*M1*C1P;
    if (i < 9*M2*C2P) {
        int rs = i / (M2*C2P), r2 = i % (M2*C2P);
        int mm = r2 / C2P, c = r2 % C2P;
        float x = (c < M1) ? c2w[(size_t)mm*2025 + c*9 + rs] : 0.f;
        split3(x, h, m, l);
        ((ushort*)(ws + O_W2H))[i] = h;
        ((ushort*)(ws + O_W2M))[i] = m;
        ((ushort*)(ws + O_W2L))[i] = l;
    }
}

// ===================== stage 1: rgb distance =====================
__global__ void k_rgb_d(const float* __restrict__ x, const float* __restrict__ rgbw,
                        float* __restrict__ D) {
    __shared__ float lw[ORGB*3];
    __shared__ float lwsq[ORGB];
    int tid = threadIdx.x;
    if (tid < ORGB*3) lw[tid] = rgbw[tid];
    __syncthreads();
    if (tid < ORGB) {
        float a = lw[tid*3], b = lw[tid*3+1], c = lw[tid*3+2];
        lwsq[tid] = 25.0f*(a*a + b*b + c*c);
    }
    __syncthreads();
    int p = blockIdx.x*256 + tid;
    int b = blockIdx.y;
    int y = p / 96, xx = p % 96;
    const float* xb = x + (size_t)b*3*10000;
    float s1_0 = 0, s1_1 = 0, s1_2 = 0, s2 = 0;
    #pragma unroll
    for (int r = 0; r < 5; ++r)
        #pragma unroll
        for (int s = 0; s < 5; ++s) {
            int off = (y+r)*100 + (xx+s);
            float v0 = xb[off], v1 = xb[10000+off], v2 = xb[20000+off];
            s1_0 += v0; s1_1 += v1; s1_2 += v2;
            s2 += v0*v0 + v1*v1 + v2*v2;
        }
    float* Db = D + (size_t)b*ORGB*L1N + p;
    for (int o = 0; o < ORGB; ++o) {
        float dot = lw[o*3]*s1_0 + lw[o*3+1]*s1_1 + lw[o*3+2]*s1_2;
        float d2 = s2 + lwsq[o] - 2.0f*dot;
        Db[(size_t)o*L1N] = sqrtf(fmaxf(d2, 0.0f));
    }
}

// ===================== stage 1: gray distance =====================
__global__ void k_gray_d(const float* __restrict__ x, const float* __restrict__ gw,
                         float* __restrict__ D) {
    __shared__ float lw[625];
    __shared__ float lwsq[25];
    int tid = threadIdx.x;
    for (int i = tid; i < 625; i += 256) lw[i] = gw[i];
    __syncthreads();
    if (tid < 25) {
        float s = 0.f;
        for (int k = 0; k < 25; ++k) { float v = lw[tid*25+k]; s += v*v; }
        lwsq[tid] = s;
    }
    __syncthreads();
    int p = blockIdx.x*256 + tid;
    int b = blockIdx.y;
    int y = p / 96, xx = p % 96;
    const float* xb = x + (size_t)b*3*10000;
    float pv[25]; float psum = 0.f;
    #pragma unroll
    for (int r = 0; r < 5; ++r)
        #pragma unroll
        for (int s = 0; s < 5; ++s) {
            int off = (y+r)*100 + (xx+s);
            float g = 0.2989f*xb[off] + 0.587f*xb[10000+off] + 0.114f*xb[20000+off];
            pv[r*5+s] = g; psum += g*g;
        }
    float* Db = D + (size_t)b*OGRAY*L1N + p;
    for (int o = 0; o < 25; ++o) {
        float dot = 0.f;
        #pragma unroll
        for (int k = 0; k < 25; ++k) dot += lw[o*25+k]*pv[k];
        float d2 = psum + lwsq[o] - 2.0f*dot;
        Db[(size_t)o*L1N] = sqrtf(fmaxf(d2, 0.0f));
    }
}

// ===================== exact rank selection: histogram pass =====================
__global__ void k_hist(const float* __restrict__ d, int perBatch, uint* __restrict__ hist,
                       const uint2* __restrict__ state, int shift, uint pmask) {
    __shared__ uint lh[2048];
    int tid = threadIdx.x;
    for (int i = tid; i < 2048; i += 256) lh[i] = 0u;
    __syncthreads();
    int b = blockIdx.y;
    uint pref = state[b].x;
    const float* db = d + (size_t)b*perBatch;
    for (int i = blockIdx.x*256 + tid; i < perBatch; i += 256*32) {
        uint bits = __float_as_uint(db[i]);
        if ((bits & pmask) == pref)
            atomicAdd(&lh[(bits >> shift) & 2047u], 1u);
    }
    __syncthreads();
    uint* hb = hist + (size_t)b*2048;
    for (int i = tid; i < 2048; i += 256) {
        uint v = lh[i];
        if (v) atomicAdd(&hb[i], v);
    }
}

// ===================== selection: scan + state update (+zero hist) =====================
__global__ void k_scan(uint* __restrict__ hist, uint2* __restrict__ state, int shift,
                       int isFinal, float* __restrict__ thr_out, const float* __restrict__ wcap) {
    __shared__ uint ss[256];
    int b = blockIdx.x, t = threadIdx.x;
    uint* hb = hist + (size_t)b*2048;
    uint bins[8]; uint seg = 0;
    #pragma unroll
    for (int i = 0; i < 8; ++i) { bins[i] = hb[t*8+i]; seg += bins[i]; }
    ss[t] = seg;
    __syncthreads();
    for (int off = 1; off < 256; off <<= 1) {
        uint add = (t >= off) ? ss[t-off] : 0u;
        __syncthreads();
        ss[t] += add;
        __syncthreads();
    }
    uint incl = ss[t], excl = incl - seg;
    uint rank = state[b].y;
    if (excl < rank && rank <= incl) {
        uint c = excl;
        #pragma unroll
        for (int i = 0; i < 8; ++i) {
            c += bins[i];
            if (c >= rank) {
                uint bin = (uint)(t*8+i);
                uint pref = state[b].x | (bin << shift);
                if (isFinal) {
                    thr_out[b] = fminf(__uint_as_float(pref), wcap[0]);
                } else {
                    state[b] = make_uint2(pref, rank - (c - bins[i]));
                }
                break;
            }
        }
    }
    __syncthreads();
    #pragma unroll
    for (int i = 0; i < 8; ++i) hb[t*8+i] = 0u;
}

// ===================== triangle + concat + sfm(2,2) -> channel-last X1' splits =====================
__global__ void k_tri_sfm1(const float* __restrict__ Drgb, const float* __restrict__ Dgray,
                           const float* __restrict__ thrA, const float* __restrict__ thrB,
                           const float* __restrict__ w1, ushort* __restrict__ XH,
                           ushort* __restrict__ XM, ushort* __restrict__ XL) {
    int idx = blockIdx.x*256 + threadIdx.x;   // 32*2500*16 = 1,280,000
    int oct = idx & 15;
    int rest = idx >> 4;                      // b*2500 + q
    int q = rest % PLANE1, b = rest / PLANE1;
    int pi = q / 50, pj = q % 50;
    bool border = (pi == 0 || pi == 49 || pj == 0 || pj == 49);
    float invw = 1.0f / w1[0];
    float tA = thrA[b], tB = thrB[b];
    int base = (2*(pi-1))*96 + 2*(pj-1);
    ushort h[8], m[8], l[8];
    #pragma unroll
    for (int j8 = 0; j8 < 8; ++j8) {
        int c = oct*8 + j8;
        float v = 0.f;
        if (!border && c < C1) {
            const float* src; float thr;
            if (c < ORGB) { src = Drgb + ((size_t)b*ORGB + c)*L1N; thr = tA; }
            else          { src = Dgray + ((size_t)b*OGRAY + (c-ORGB))*L1N; thr = tB; }
            float d00 = src[base], d01 = src[base+1], d10 = src[base+96], d11 = src[base+97];
            float t00 = d00 > thr ? 0.f : 1.f - d00*invw;
            float t01 = d01 > thr ? 0.f : 1.f - d01*invw;
            float t10 = d10 > thr ? 0.f : 1.f - d10*invw;
            float t11 = d11 > thr ? 0.f : 1.f - d11*invw;
            v = 0.25f*(0.9f*t00 + 0.93f*t01 + 0.96f*t10 + 0.99f*t11);
        }
        split3(v, h[j8], m[j8], l[j8]);
    }
    size_t ob = (size_t)rest * C1P + oct*8;
    uint4 ph, pm, pl;
    ph.x = (uint)h[0] | ((uint)h[1]<<16); ph.y = (uint)h[2] | ((uint)h[3]<<16);
    ph.z = (uint)h[4] | ((uint)h[5]<<16); ph.w = (uint)h[6] | ((uint)h[7]<<16);
    pm.x = (uint)m[0] | ((uint)m[1]<<16); pm.y = (uint)m[2] | ((uint)m[3]<<16);
    pm.z = (uint)m[4] | ((uint)m[5]<<16); pm.w = (uint)m[6] | ((uint)m[7]<<16);
    pl.x = (uint)l[0] | ((uint)l[1]<<16); pl.y = (uint)l[2] | ((uint)l[3]<<16);
    pl.z = (uint)l[4] | ((uint)l[5]<<16); pl.w = (uint)l[6] | ((uint)l[7]<<16);
    *(uint4*)&XH[ob] = ph; *(uint4*)&XM[ob] = pm; *(uint4*)&XL[ob] = pl;
}

// ===================== channel-sum of squares (padded plane, channel-last) =====================
__global__ void k_z1(const ushort* __restrict__ XH, const ushort* __restrict__ XM,
                     const ushort* __restrict__ XL, float* __restrict__ Zp) {
    int idx = blockIdx.x*256 + threadIdx.x;
    if (idx >= NB*PLANE1) return;
    size_t base = (size_t)idx * C1P;
    float s = 0.f;
    for (int oct = 0; oct < 16; ++oct) {
        uint4 ph = *(const uint4*)&XH[base + oct*8];
        uint4 pm = *(const uint4*)&XM[base + oct*8];
        uint4 pl = *(const uint4*)&XL[base + oct*8];
        const uint* hu = (const uint*)&ph; const uint* mu = (const uint*)&pm;
        const uint* lu = (const uint*)&pl;
        #pragma unroll
        for (int w = 0; w < 4; ++w) {
            float v0 = bf16_f32((ushort)(hu[w] & 0xFFFF)) + bf16_f32((ushort)(mu[w] & 0xFFFF))
                     + bf16_f32((ushort)(lu[w] & 0xFFFF));
            float v1 = bf16_f32((ushort)(hu[w] >> 16)) + bf16_f32((ushort)(mu[w] >> 16))
                     + bf16_f32((ushort)(lu[w] >> 16));
            s += v0*v0 + v1*v1;
        }
    }
    Zp[idx] = s;
}

__global__ void k_psq1(const float* __restrict__ Zp, float* __restrict__ psq) {
    int idx = blockIdx.x*256 + threadIdx.x;   // exactly 32*2304
    int b = idx / P1, p = idx % P1;
    int y = p / 48, x = p % 48;
    const float* zb = Zp + (size_t)b*PLANE1;
    float s = 0.f;
    #pragma unroll
    for (int r = 0; r < 3; ++r)
        #pragma unroll
        for (int c = 0; c < 3; ++c) s += zb[(y+r)*50 + x + c];
    psq[idx] = s;
}

// ===================== shifted-tap MFMA GEMM, LDS-staged B =====================
// Per K-chunk: stage the block's <=300-pixel input window (3 splits x 4 quads)
// into LDS once, then 9 taps read B-frags via ds_read_b128 (reuse 9x).
// LDS layout [split][px][quad]: byte addr = sp*24000 + px*80 + q*16
//   - frag reads: lanes 0-15 consecutive px, stride 80 B -> 2-way aliasing (free, m136)
//   - staging writes: q fastest -> 64 B contiguous per 4 lanes -> 2-way (free)
// 6 bf16-split products per (chunk, tap): hh, mh, lh, hm, mm, hl.
__global__ __launch_bounds__(256, 2) void k_gemm_mfma(
        const ushort* __restrict__ Wh, const ushort* __restrict__ Wm, const ushort* __restrict__ Wl,
        const ushort* __restrict__ Xh, const ushort* __restrict__ Xm, const ushort* __restrict__ Xl,
        const float* __restrict__ psq, const float* __restrict__ wsq, float* __restrict__ Dout,
        int M, int CP, int OW, int PW, int PLN, int Nper, int KB) {
    __shared__ ushort Bsm[36000];   // 72 KB: [3][300][40 ushorts]

    int tid = threadIdx.x;
    int batch = blockIdx.x / KB;
    int kblk  = blockIdx.x % KB;
    int p0 = kblk*192; if (p0 + 192 > Nper) p0 = Nper - 192;   // overlap: dup writes identical
    int m0 = blockIdx.y*128; if (m0 + 128 > M)  m0 = M - 128;
    int lane = tid & 63, wid = tid >> 6;
    int wy = wid >> 1, wx = wid & 1;
    int quad = lane >> 4, ln = lane & 15;

    int R0  = p0 / OW;
    int NR  = (p0 + 191) / OW + 2 - R0 + 1;    // rows incl. +2 tap halo (<=12)
    int NPX = NR * PW;                          // <= 300
    size_t gpix0 = (size_t)batch * PLN + (size_t)R0 * PW;

    int aoff[4];
    #pragma unroll
    for (int mt = 0; mt < 4; ++mt)
        aoff[mt] = (m0 + wy*64 + mt*16 + ln)*CP + quad*8;
    int baseN[6];
    #pragma unroll
    for (int nt = 0; nt < 6; ++nt) {
        int p = p0 + wx*96 + nt*16 + ln;
        baseN[nt] = (p/OW - R0)*PW + (p % OW);
    }

    f32x4 acc[4][6];
    #pragma unroll
    for (int mt = 0; mt < 4; ++mt)
        #pragma unroll
        for (int nt = 0; nt < 6; ++nt) acc[mt][nt] = (f32x4){0.f, 0.f, 0.f, 0.f};

    int MC = M*CP;
    for (int c0 = 0; c0 < CP; c0 += 32) {
        __syncthreads();                        // protect prior chunk's reads
        int units = 12 * NPX;                   // 3 splits x 4 quads x NPX pixels
        for (int u = tid; u < units; u += 256) {
            int q  = u & 3;
            int rem = u >> 2;                   // sp*NPX + px
            int sp = rem / NPX, px = rem - sp*NPX;
            const ushort* Xs = (sp == 0) ? Xh : ((sp == 1) ? Xm : Xl);
            uint4 v = *(const uint4*)(Xs + (gpix0 + px)*CP + c0 + q*8);
            *(uint4*)&Bsm[sp*12000 + px*40 + q*8] = v;
        }
        __syncthreads();

        for (int r = 0; r < 3; ++r)
        for (int st = 0; st < 3; ++st) {
            int soffA = (r*3 + st)*MC + c0;
            int tb = (r*PW + st)*40 + quad*8;
            bf16x8 af0[4], af1[4], af2[4];
            #pragma unroll
            for (int mt = 0; mt < 4; ++mt) {
                int ao = soffA + aoff[mt];
                af0[mt] = *(const bf16x8*)(Wh + ao);
                af1[mt] = *(const bf16x8*)(Wm + ao);
                af2[mt] = *(const bf16x8*)(Wl + ao);
            }
            bf16x8 bf[6];
            #pragma unroll
            for (int nt = 0; nt < 6; ++nt)
                bf[nt] = *(const bf16x8*)&Bsm[baseN[nt]*40 + tb];
            #pragma unroll
            for (int mt = 0; mt < 4; ++mt)
                #pragma unroll
                for (int nt = 0; nt < 6; ++nt)
                    acc[mt][nt] = __builtin_amdgcn_mfma_f32_16x16x32_bf16(af0[mt], bf[nt], acc[mt][nt], 0, 0, 0);
            #pragma unroll
            for (int mt = 0; mt < 4; ++mt)
                #pragma unroll
                for (int nt = 0; nt < 6; ++nt)
                    acc[mt][nt] = __builtin_amdgcn_mfma_f32_16x16x32_bf16(af1[mt], bf[nt], acc[mt][nt], 0, 0, 0);
            #pragma unroll
            for (int mt = 0; mt < 4; ++mt)
                #pragma unroll
                for (int nt = 0; nt < 6; ++nt)
                    acc[mt][nt] = __builtin_amdgcn_mfma_f32_16x16x32_bf16(af2[mt], bf[nt], acc[mt][nt], 0, 0, 0);
            #pragma unroll
            for (int nt = 0; nt < 6; ++nt)
                bf[nt] = *(const bf16x8*)&Bsm[12000 + baseN[nt]*40 + tb];
            #pragma unroll
            for (int mt = 0; mt < 4; ++mt)
                #pragma unroll
                for (int nt = 0; nt < 6; ++nt)
                    acc[mt][nt] = __builtin_amdgcn_mfma_f32_16x16x32_bf16(af0[mt], bf[nt], acc[mt][nt], 0, 0, 0);
            #pragma unroll
            for (int mt = 0; mt < 4; ++mt)
                #pragma unroll
                for (int nt = 0; nt < 6; ++nt)
                    acc[mt][nt] = __builtin_amdgcn_mfma_f32_16x16x32_bf16(af1[mt], bf[nt], acc[mt][nt], 0, 0, 0);
            #pragma unroll
            for (int nt = 0; nt < 6; ++nt)
                bf[nt] = *(const bf16x8*)&Bsm[24000 + baseN[nt]*40 + tb];
            #pragma unroll
            for (int mt = 0; mt < 4; ++mt)
                #pragma unroll
                for (int nt = 0; nt < 6; ++nt)
                    acc[mt][nt] = __builtin_amdgcn_mfma_f32_16x16x32_bf16(af0[mt], bf[nt], acc[mt][nt], 0, 0, 0);
        }
    }

    // epilogue: C/D layout col=lane&15, row=quad*4+reg
    #pragma unroll
    for (int mt = 0; mt < 4; ++mt) {
        int gmb = m0 + wy*64 + mt*16 + (quad << 2);
        float4 w4 = *(const float4*)&wsq[gmb];
        #pragma unroll
        for (int nt = 0; nt < 6; ++nt) {
            int p = p0 + wx*96 + nt*16 + ln;
            float ps = psq[batch*Nper + p];
            size_t ob = (size_t)batch*M*Nper + p;
            f32x4 a = acc[mt][nt];
            Dout[ob + (size_t)(gmb+0)*Nper] = sqrtf(fmaxf(ps + w4.x - 2.0f*a.x, 0.f));
            Dout[ob + (size_t)(gmb+1)*Nper] = sqrtf(fmaxf(ps + w4.y - 2.0f*a.y, 0.f));
            Dout[ob + (size_t)(gmb+2)*Nper] = sqrtf(fmaxf(ps + w4.z - 2.0f*a.z, 0.f));
            Dout[ob + (size_t)(gmb+3)*Nper] = sqrtf(fmaxf(ps + w4.w - 2.0f*a.w, 0.f));
        }
    }
}

// ===================== triangle + sfm(2,2) after conv1 -> channel-last X2' splits =====================
__global__ void k_tri_sfm2(const float* __restrict__ D1, const float* __restrict__ thr2,
                           const float* __restrict__ w2, ushort* __restrict__ XH,
                           ushort* __restrict__ XM, ushort* __restrict__ XL) {
    int idx = blockIdx.x*256 + threadIdx.x;   // 32*576*32 = 589,824
    int oct = idx & 31;
    int rest = idx >> 5;                      // b*576 + q
    int q = rest % P2, b = rest / P2;
    int i = q / 24, j = q % 24;
    float thr = thr2[b], invw = 1.0f / w2[0];
    int base = (2*i)*48 + 2*j;
    ushort h[8], m[8], l[8];
    #pragma unroll
    for (int j8 = 0; j8 < 8; ++j8) {
        int c = oct*8 + j8;
        float v = 0.f;
        if (c < M1) {
            const float* src = D1 + ((size_t)b*M1 + c)*P1;
            float d00 = src[base], d01 = src[base+1], d10 = src[base+48], d11 = src[base+49];
            float t00 = d00 > thr ? 0.f : 1.f - d00*invw;
            float t01 = d01 > thr ? 0.f : 1.f - d01*invw;
            float t10 = d10 > thr ? 0.f : 1.f - d10*invw;
            float t11 = d11 > thr ? 0.f : 1.f - d11*invw;
            v = 0.25f*(0.9f*t00 + 0.93f*t01 + 0.96f*t10 + 0.99f*t11);
        }
        split3(v, h[j8], m[j8], l[j8]);
    }
    size_t ob = (size_t)rest * C2P + oct*8;
    uint4 ph, pm, pl;
    ph.x = (uint)h[0] | ((uint)h[1]<<16); ph.y = (uint)h[2] | ((uint)h[3]<<16);
    ph.z = (uint)h[4] | ((uint)h[5]<<16); ph.w = (uint)h[6] | ((uint)h[7]<<16);
    pm.x = (uint)m[0] | ((uint)m[1]<<16); pm.y = (uint)m[2] | ((uint)m[3]<<16);
    pm.z = (uint)m[4] | ((uint)m[5]<<16); pm.w = (uint)m[6] | ((uint)m[7]<<16);
    pl.x = (uint)l[0] | ((uint)l[1]<<16); pl.y = (uint)l[2] | ((uint)l[3]<<16);
    pl.z = (uint)l[4] | ((uint)l[5]<<16); pl.w = (uint)l[6] | ((uint)l[7]<<16);
    *(uint4*)&XH[ob] = ph; *(uint4*)&XM[ob] = pm; *(uint4*)&XL[ob] = pl;
}

__global__ void k_z2(const ushort* __restrict__ XH, const ushort* __restrict__ XM,
                     const ushort* __restrict__ XL, float* __restrict__ Z2) {
    int idx = blockIdx.x*256 + threadIdx.x;
    if (idx >= NB*P2) return;
    size_t base = (size_t)idx * C2P;
    float s = 0.f;
    for (int oct = 0; oct < 32; ++oct) {
        uint4 ph = *(const uint4*)&XH[base + oct*8];
        uint4 pm = *(const uint4*)&XM[base + oct*8];
        uint4 pl = *(const uint4*)&XL[base + oct*8];
        const uint* hu = (const uint*)&ph; const uint* mu = (const uint*)&pm;
        const uint* lu = (const uint*)&pl;
        #pragma unroll
        for (int w = 0; w < 4; ++w) {
            float v0 = bf16_f32((ushort)(hu[w] & 0xFFFF)) + bf16_f32((ushort)(mu[w] & 0xFFFF))
                     + bf16_f32((ushort)(lu[w] & 0xFFFF));
            float v1 = bf16_f32((ushort)(hu[w] >> 16)) + bf16_f32((ushort)(mu[w] >> 16))
                     + bf16_f32((ushort)(lu[w] >> 16));
            s += v0*v0 + v1*v1;
        }
    }
    Z2[idx] = s;
}

__global__ void k_psq2(const float* __restrict__ Z2, float* __restrict__ psq) {
    int idx = blockIdx.x*256 + threadIdx.x;
    if (idx >= NB*N2) return;
    int b = idx / N2, p = idx % N2;
    int y = p / 22, x = p % 22;
    const float* zb = Z2 + (size_t)b*P2;
    float s = 0.f;
    #pragma unroll
    for (int r = 0; r < 3; ++r)
        #pragma unroll
        for (int c = 0; c < 3; ++c) s += zb[(y+r)*24 + x + c];
    psq[idx] = s;
}

// ===================== triangle + FC =====================
__global__ void k_fc(const float* __restrict__ D2, const float* __restrict__ fcw,
                     const float* __restrict__ thr3, const float* __restrict__ w3,
                     float* __restrict__ out) {
    int tid = threadIdx.x, b = blockIdx.y;
    float thr = thr3[b];
    float invw = 1.0f / w3[0];
    const float* db = D2 + (size_t)b*FCN;
    float acc[10];
    #pragma unroll
    for (int o = 0; o < 10; ++o) acc[o] = 0.f;
    int base = blockIdx.x*2048;
    #pragma unroll
    for (int it = 0; it < 8; ++it) {
        int p = base + it*256 + tid;
        if (p < FCN) {
            float v = db[p];
            float tv = v > thr ? 0.f : 1.f - v*invw;
            #pragma unroll
            for (int o = 0; o < 10; ++o) acc[o] += tv * fcw[(size_t)o*FCN + p];
        }
    }
    #pragma unroll
    for (int o = 0; o < 10; ++o)
        #pragma unroll
        for (int off = 32; off; off >>= 1) acc[o] += __shfl_down(acc[o], off);
    __shared__ float red[4][10];
    int lane = tid & 63, wid = tid >> 6;
    if (lane == 0) {
        #pragma unroll
        for (int o = 0; o < 10; ++o) red[wid][o] = acc[o];
    }
    __syncthreads();
    if (tid < 10) {
        float s = red[0][tid] + red[1][tid] + red[2][tid] + red[3][tid];
        atomicAdd(&out[b*10 + tid], s);
    }
}

// ===================== launch =====================
extern "C" void kernel_launch(void* const* d_in, const int* in_sizes, int n_in,
                              void* d_out, int out_size, void* d_ws, size_t ws_size,
                              hipStream_t stream) {
    const float* x    = (const float*)d_in[0];
    const float* rgbw = (const float*)d_in[1];
    const float* gryw = (const float*)d_in[2];
    const float* c1w  = (const float*)d_in[3];
    const float* c2w  = (const float*)d_in[4];
    const float* fcw  = (const float*)d_in[5];
    const float* fcb  = (const float*)d_in[6];
    const float* w1   = (const float*)d_in[7];
    const float* w2   = (const float*)d_in[8];
    const float* w3   = (const float*)d_in[9];
    float* out = (float*)d_out;
    float* ws  = (float*)d_ws;

    float* Drgb  = ws + O_A;
    float* Dgray = ws + O_B;
    uint*  hist  = (uint*)(ws + O_HIST);
    uint2* state = (uint2*)(ws + O_STATE);
    float* thr   = ws + O_THR;

    // init threads: 65536 + 320 + 128 = 65,984 -> 258 blocks
    k_tables<<<258, 256, 0, stream>>>(ws, fcb, out);
    k_wsq<<<M1 + M2, 64, 0, stream>>>(c1w, c2w, ws);
    k_rgb_d<<<dim3(36, 32), 256, 0, stream>>>(x, rgbw, Drgb);
    k_gray_d<<<dim3(36, 32), 256, 0, stream>>>(x, gryw, Dgray);

    auto sel = [&](const float* dptr, int perBatch, uint2* st, float* thro, const float* wc) {
        const int shifts[3] = {21, 10, 0};
        const uint masks[3] = {0u, 0xFFE00000u, 0xFFFFFC00u};
        for (int p = 0; p < 3; ++p) {
            k_hist<<<dim3(32, 32), 256, 0, stream>>>(dptr, perBatch, hist, st, shifts[p], masks[p]);
            k_scan<<<32, 256, 0, stream>>>(hist, st, shifts[p], p == 2, thro, wc);
        }
    };

    sel(Drgb, ORGB*L1N, state + 0,  thr + 0,  w1);
    sel(Dgray, OGRAY*L1N, state + 32, thr + 32, w1);

    k_tri_sfm1<<<5000, 256, 0, stream>>>(Drgb, Dgray, thr + 0, thr + 32, w1,
        (ushort*)(ws + O_X1H), (ushort*)(ws + O_X1M), (ushort*)(ws + O_X1L));
    // W splits overlay the (now dead) Dgray region: 259,200 + 1,440,000 threads -> 6638 blocks
    k_splitw<<<6638, 256, 0, stream>>>(c1w, c2w, ws);
    k_z1<<<313, 256, 0, stream>>>((const ushort*)(ws + O_X1H), (const ushort*)(ws + O_X1M),
        (const ushort*)(ws + O_X1L), ws + O_ZP1);
    k_psq1<<<288, 256, 0, stream>>>(ws + O_ZP1, ws + O_PSQ1);

    float* D1 = ws + O_A;
    // gemm1: 12 n-blocks/batch x 32 batches, 2 m-tiles
    k_gemm_mfma<<<dim3(12*NB, 2), 256, 0, stream>>>(
        (const ushort*)(ws + O_W1H), (const ushort*)(ws + O_W1M), (const ushort*)(ws + O_W1L),
        (const ushort*)(ws + O_X1H), (const ushort*)(ws + O_X1M), (const ushort*)(ws + O_X1L),
        ws + O_PSQ1, ws + O_WSQ1, D1, M1, C1P, 48, 50, PLANE1, P1, 12);

    sel(D1, M1*P1, state + 64, thr + 64, w2);

    k_tri_sfm2<<<2304, 256, 0, stream>>>(D1, thr + 64, w2,
        (ushort*)(ws + O_X2H), (ushort*)(ws + O_X2M), (ushort*)(ws + O_X2L));
    k_z2<<<72, 256, 0, stream>>>((const ushort*)(ws + O_X2H), (const ushort*)(ws + O_X2M),
        (const ushort*)(ws + O_X2L), ws + O_Z2);
    k_psq2<<<61, 256, 0, stream>>>(ws + O_Z2, ws + O_PSQ2);

    float* D2 = ws + O_A;
    // gemm2: 3 n-blocks/batch x 32 batches, 5 m-tiles
    k_gemm_mfma<<<dim3(3*NB, 5), 256, 0, stream>>>(
        (const ushort*)(ws + O_W2H), (const ushort*)(ws + O_W2M), (const ushort*)(ws + O_W2L),
        (const ushort*)(ws + O_X2H), (const ushort*)(ws + O_X2M), (const ushort*)(ws + O_X2L),
        ws + O_PSQ2, ws + O_WSQ2, D2, M2, C2P, 22, 24, P2, N2, 3);

    sel(D2, FCN, state + 96, thr + 96, w3);

    k_fc<<<dim3(148, 32), 256, 0, stream>>>(D2, fcw, thr + 96, w3, out);
}

// Round 10
// 1187.853 us; speedup vs baseline: 1.3204x; 1.0218x over previous
//
#include <hip/hip_runtime.h>

typedef unsigned int uint;
typedef unsigned short ushort;

#define NB 32

// geometry
#define L1N 9216      // 96*96
#define ORGB 75
#define OGRAY 25
#define C1 100
#define C1P 128       // channel pad, layer-1 GEMM
#define PLANE1 2500   // 50*50 padded
#define P1 2304       // 48*48
#define M1 225
#define P2 576        // 24*24
#define M2 625
#define C2P 256       // channel pad, layer-2 GEMM (M1=225 -> 256)
#define N2 484        // 22*22
#define FCN 302500    // 625*484
#define NT1 73728     // 2304*32 merged columns
#define NT2 15488     // 484*32 merged columns

// exact ranks: ceil(percent*N) evaluated in fp64
#define KK0 345600u
#define KK1 115200u
#define KK2 207360u
#define KK3 121000u

// ---- workspace layout (float-element offsets) ----
constexpr size_t O_A     = 0;                       // Drgb 22,118,400 -> D1 16.6M -> D2 9.68M
constexpr size_t O_B     = 22118400;                // Dgray 7,372,800 ; W overlays after tri_sfm1
constexpr size_t O_W1H   = O_B;                     // 9*225*128 ushorts = 129,600 floats each
constexpr size_t O_W1M   = O_B + 129600;
constexpr size_t O_W1L   = O_B + 259200;
constexpr size_t O_W2H   = O_B + 388800;            // 9*625*256 ushorts = 720,000 floats each
constexpr size_t O_W2M   = O_B + 1108800;
constexpr size_t O_W2L   = O_B + 1828800;           // end 2,548,800 <= 7,372,800
constexpr size_t O_X     = 29491200;                // X' channel-last split planes
constexpr size_t O_X1H   = O_X;                     // 32*2500*128 ushorts = 5,120,000 floats each
constexpr size_t O_X1M   = O_X + 5120000;
constexpr size_t O_X1L   = O_X + 10240000;
constexpr size_t O_X2H   = O_X;                     // overlay: 32*576*256 ushorts = 2,359,296 floats
constexpr size_t O_X2M   = O_X + 2359296;
constexpr size_t O_X2L   = O_X + 4718592;
constexpr size_t O_HIST  = O_X + 15360000;          // 44,851,200 ; 65,536 uints
constexpr size_t O_STATE = O_HIST + 65536;          // 128 uint2
constexpr size_t O_THR   = O_STATE + 256;
constexpr size_t O_WSQ1  = O_THR + 128;
constexpr size_t O_WSQ2  = O_WSQ1 + 256;
constexpr size_t O_ZP1   = O_WSQ2 + 640;            // 80,000
constexpr size_t O_PSQ1  = O_ZP1 + 80000;           // 73,728
constexpr size_t O_Z2    = O_PSQ1 + 73728;          // 18,432
constexpr size_t O_PSQ2  = O_Z2 + 18432;            // 15,488
constexpr size_t O_END   = O_PSQ2 + 15488;          // ~180.7 MB

// ---- bf16 helpers (RNE) ----
__device__ __forceinline__ ushort bf16_rne(float x) {
    uint u = __float_as_uint(x);
    uint r = u + 0x7FFFu + ((u >> 16) & 1u);
    return (ushort)(r >> 16);
}
__device__ __forceinline__ float bf16_f32(ushort h) {
    return __uint_as_float(((uint)h) << 16);
}
__device__ __forceinline__ void split3(float v, ushort& h, ushort& m, ushort& l) {
    h = bf16_rne(v);           float hf = bf16_f32(h);
    m = bf16_rne(v - hf);      float mf = bf16_f32(m);
    l = bf16_rne(v - hf - mf);
}

typedef __attribute__((ext_vector_type(8))) short bf16x8;
typedef __attribute__((ext_vector_type(4))) float f32x4;
typedef __attribute__((ext_vector_type(16))) float f32x16;

// ===================== init: zero hist, states, out=bias =====================
__global__ void k_tables(float* ws, const float* fcb, float* out) {
    int i = blockIdx.x*256 + threadIdx.x;
    if (i < 65536) { ((uint*)(ws + O_HIST))[i] = 0u; return; }
    i -= 65536;
    if (i < 320) { out[i] = fcb[i % 10]; return; }
    i -= 320;
    if (i < 128) {
        const uint kks[4] = {KK0, KK1, KK2, KK3};
        ((uint2*)(ws + O_STATE))[i] = make_uint2(0u, kks[i >> 5]);
    }
}

// ===================== per-row squared norms of conv weights =====================
__global__ void k_wsq(const float* c1w, const float* c2w, float* ws) {
    int o = blockIdx.x, lane = threadIdx.x;   // 64 threads
    const float* row; int K; float* dst;
    if (o < M1) { row = c1w + (size_t)o*900; K = 900; dst = ws + O_WSQ1 + o; }
    else { int oo = o - M1; row = c2w + (size_t)oo*2025; K = 2025; dst = ws + O_WSQ2 + oo; }
    float s = 0.f;
    for (int k = lane; k < K; k += 64) { float v = row[k]; s += v*v; }
    #pragma unroll
    for (int off = 32; off; off >>= 1) s += __shfl_down(s, off);
    if (lane == 0) *dst = s;
}

// ===================== split W into tap-major bf16 planes Wrs[9][M][C'] =====================
__global__ void k_splitw(const float* __restrict__ c1w, const float* __restrict__ c2w,
                         float* __restrict__ ws) {
    int i = blockIdx.x*256 + threadIdx.x;
    ushort h, m, l;
    if (i < 9*M1*C1P) {
        int rs = i / (M1*C1P), r2 = i % (M1*C1P);
        int mm = r2 / C1P, c = r2 % C1P;
        float x = (c < C1) ? c1w[(size_t)mm*900 + c*9 + rs] : 0.f;
        split3(x, h, m, l);
        ((ushort*)(ws + O_W1H))[i] = h;
        ((ushort*)(ws + O_W1M))[i] = m;
        ((ushort*)(ws + O_W1L))[i] = l;
        return;
    }
    i -= 9*M1*C1P;
    if (i < 9*M2*C2P) {
        int rs = i / (M2*C2P), r2 = i % (M2*C2P);
        int mm = r2 / C2P, c = r2 % C2P;
        float x = (c < M1) ? c2w[(size_t)mm*2025 + c*9 + rs] : 0.f;
        split3(x, h, m, l);
        ((ushort*)(ws + O_W2H))[i] = h;
        ((ushort*)(ws + O_W2M))[i] = m;
        ((ushort*)(ws + O_W2L))[i] = l;
    }
}

// ===================== stage 1: rgb distance =====================
__global__ void k_rgb_d(const float* __restrict__ x, const float* __restrict__ rgbw,
                        float* __restrict__ D) {
    __shared__ float lw[ORGB*3];
    __shared__ float lwsq[ORGB];
    int tid = threadIdx.x;
    if (tid < ORGB*3) lw[tid] = rgbw[tid];
    __syncthreads();
    if (tid < ORGB) {
        float a = lw[tid*3], b = lw[tid*3+1], c = lw[tid*3+2];
        lwsq[tid] = 25.0f*(a*a + b*b + c*c);
    }
    __syncthreads();
    int p = blockIdx.x*256 + tid;
    int b = blockIdx.y;
    int y = p / 96, xx = p % 96;
    const float* xb = x + (size_t)b*3*10000;
    float s1_0 = 0, s1_1 = 0, s1_2 = 0, s2 = 0;
    #pragma unroll
    for (int r = 0; r < 5; ++r)
        #pragma unroll
        for (int s = 0; s < 5; ++s) {
            int off = (y+r)*100 + (xx+s);
            float v0 = xb[off], v1 = xb[10000+off], v2 = xb[20000+off];
            s1_0 += v0; s1_1 += v1; s1_2 += v2;
            s2 += v0*v0 + v1*v1 + v2*v2;
        }
    float* Db = D + (size_t)b*ORGB*L1N + p;
    for (int o = 0; o < ORGB; ++o) {
        float dot = lw[o*3]*s1_0 + lw[o*3+1]*s1_1 + lw[o*3+2]*s1_2;
        float d2 = s2 + lwsq[o] - 2.0f*dot;
        Db[(size_t)o*L1N] = sqrtf(fmaxf(d2, 0.0f));
    }
}

// ===================== stage 1: gray distance =====================
__global__ void k_gray_d(const float* __restrict__ x, const float* __restrict__ gw,
                         float* __restrict__ D) {
    __shared__ float lw[625];
    __shared__ float lwsq[25];
    int tid = threadIdx.x;
    for (int i = tid; i < 625; i += 256) lw[i] = gw[i];
    __syncthreads();
    if (tid < 25) {
        float s = 0.f;
        for (int k = 0; k < 25; ++k) { float v = lw[tid*25+k]; s += v*v; }
        lwsq[tid] = s;
    }
    __syncthreads();
    int p = blockIdx.x*256 + tid;
    int b = blockIdx.y;
    int y = p / 96, xx = p % 96;
    const float* xb = x + (size_t)b*3*10000;
    float pv[25]; float psum = 0.f;
    #pragma unroll
    for (int r = 0; r < 5; ++r)
        #pragma unroll
        for (int s = 0; s < 5; ++s) {
            int off = (y+r)*100 + (xx+s);
            float g = 0.2989f*xb[off] + 0.587f*xb[10000+off] + 0.114f*xb[20000+off];
            pv[r*5+s] = g; psum += g*g;
        }
    float* Db = D + (size_t)b*OGRAY*L1N + p;
    for (int o = 0; o < 25; ++o) {
        float dot = 0.f;
        #pragma unroll
        for (int k = 0; k < 25; ++k) dot += lw[o*25+k]*pv[k];
        float d2 = psum + lwsq[o] - 2.0f*dot;
        Db[(size_t)o*L1N] = sqrtf(fmaxf(d2, 0.0f));
    }
}

// ===================== exact rank selection: histogram pass =====================
__global__ void k_hist(const float* __restrict__ d, int perBatch, uint* __restrict__ hist,
                       const uint2* __restrict__ state, int shift, uint pmask) {
    __shared__ uint lh[2048];
    int tid = threadIdx.x;
    for (int i = tid; i < 2048; i += 256) lh[i] = 0u;
    __syncthreads();
    int b = blockIdx.y;
    uint pref = state[b].x;
    const float* db = d + (size_t)b*perBatch;
    for (int i = blockIdx.x*256 + tid; i < perBatch; i += 256*32) {
        uint bits = __float_as_uint(db[i]);
        if ((bits & pmask) == pref)
            atomicAdd(&lh[(bits >> shift) & 2047u], 1u);
    }
    __syncthreads();
    uint* hb = hist + (size_t)b*2048;
    for (int i = tid; i < 2048; i += 256) {
        uint v = lh[i];
        if (v) atomicAdd(&hb[i], v);
    }
}

// ===================== selection: scan + state update (+zero hist) =====================
__global__ void k_scan(uint* __restrict__ hist, uint2* __restrict__ state, int shift,
                       int isFinal, float* __restrict__ thr_out, const float* __restrict__ wcap) {
    __shared__ uint ss[256];
    int b = blockIdx.x, t = threadIdx.x;
    uint* hb = hist + (size_t)b*2048;
    uint bins[8]; uint seg = 0;
    #pragma unroll
    for (int i = 0; i < 8; ++i) { bins[i] = hb[t*8+i]; seg += bins[i]; }
    ss[t] = seg;
    __syncthreads();
    for (int off = 1; off < 256; off <<= 1) {
        uint add = (t >= off) ? ss[t-off] : 0u;
        __syncthreads();
        ss[t] += add;
        __syncthreads();
    }
    uint incl = ss[t], excl = incl - seg;
    uint rank = state[b].y;
    if (excl < rank && rank <= incl) {
        uint c = excl;
        #pragma unroll
        for (int i = 0; i < 8; ++i) {
            c += bins[i];
            if (c >= rank) {
                uint bin = (uint)(t*8+i);
                uint pref = state[b].x | (bin << shift);
                if (isFinal) {
                    thr_out[b] = fminf(__uint_as_float(pref), wcap[0]);
                } else {
                    state[b] = make_uint2(pref, rank - (c - bins[i]));
                }
                break;
            }
        }
    }
    __syncthreads();
    #pragma unroll
    for (int i = 0; i < 8; ++i) hb[t*8+i] = 0u;
}

// ===================== triangle + concat + sfm(2,2) -> channel-last X1' splits =====================
__global__ void k_tri_sfm1(const float* __restrict__ Drgb, const float* __restrict__ Dgray,
                           const float* __restrict__ thrA, const float* __restrict__ thrB,
                           const float* __restrict__ w1, ushort* __restrict__ XH,
                           ushort* __restrict__ XM, ushort* __restrict__ XL) {
    int idx = blockIdx.x*256 + threadIdx.x;   // 32*2500*16 = 1,280,000
    int oct = idx & 15;
    int rest = idx >> 4;                      // b*2500 + q
    int q = rest % PLANE1, b = rest / PLANE1;
    int pi = q / 50, pj = q % 50;
    bool border = (pi == 0 || pi == 49 || pj == 0 || pj == 49);
    float invw = 1.0f / w1[0];
    float tA = thrA[b], tB = thrB[b];
    int base = (2*(pi-1))*96 + 2*(pj-1);
    ushort h[8], m[8], l[8];
    #pragma unroll
    for (int j8 = 0; j8 < 8; ++j8) {
        int c = oct*8 + j8;
        float v = 0.f;
        if (!border && c < C1) {
            const float* src; float thr;
            if (c < ORGB) { src = Drgb + ((size_t)b*ORGB + c)*L1N; thr = tA; }
            else          { src = Dgray + ((size_t)b*OGRAY + (c-ORGB))*L1N; thr = tB; }
            float d00 = src[base], d01 = src[base+1], d10 = src[base+96], d11 = src[base+97];
            float t00 = d00 > thr ? 0.f : 1.f - d00*invw;
            float t01 = d01 > thr ? 0.f : 1.f - d01*invw;
            float t10 = d10 > thr ? 0.f : 1.f - d10*invw;
            float t11 = d11 > thr ? 0.f : 1.f - d11*invw;
            v = 0.25f*(0.9f*t00 + 0.93f*t01 + 0.96f*t10 + 0.99f*t11);
        }
        split3(v, h[j8], m[j8], l[j8]);
    }
    size_t ob = (size_t)rest * C1P + oct*8;
    uint4 ph, pm, pl;
    ph.x = (uint)h[0] | ((uint)h[1]<<16); ph.y = (uint)h[2] | ((uint)h[3]<<16);
    ph.z = (uint)h[4] | ((uint)h[5]<<16); ph.w = (uint)h[6] | ((uint)h[7]<<16);
    pm.x = (uint)m[0] | ((uint)m[1]<<16); pm.y = (uint)m[2] | ((uint)m[3]<<16);
    pm.z = (uint)m[4] | ((uint)m[5]<<16); pm.w = (uint)m[6] | ((uint)m[7]<<16);
    pl.x = (uint)l[0] | ((uint)l[1]<<16); pl.y = (uint)l[2] | ((uint)l[3]<<16);
    pl.z = (uint)l[4] | ((uint)l[5]<<16); pl.w = (uint)l[6] | ((uint)l[7]<<16);
    *(uint4*)&XH[ob] = ph; *(uint4*)&XM[ob] = pm; *(uint4*)&XL[ob] = pl;
}

// ===================== channel-sum of squares (padded plane, channel-last) =====================
__global__ void k_z1(const ushort* __restrict__ XH, const ushort* __restrict__ XM,
                     const ushort* __restrict__ XL, float* __restrict__ Zp) {
    int idx = blockIdx.x*256 + threadIdx.x;
    if (idx >= NB*PLANE1) return;
    size_t base = (size_t)idx * C1P;
    float s = 0.f;
    for (int oct = 0; oct < 16; ++oct) {
        uint4 ph = *(const uint4*)&XH[base + oct*8];
        uint4 pm = *(const uint4*)&XM[base + oct*8];
        uint4 pl = *(const uint4*)&XL[base + oct*8];
        const uint* hu = (const uint*)&ph; const uint* mu = (const uint*)&pm;
        const uint* lu = (const uint*)&pl;
        #pragma unroll
        for (int w = 0; w < 4; ++w) {
            float v0 = bf16_f32((ushort)(hu[w] & 0xFFFF)) + bf16_f32((ushort)(mu[w] & 0xFFFF))
                     + bf16_f32((ushort)(lu[w] & 0xFFFF));
            float v1 = bf16_f32((ushort)(hu[w] >> 16)) + bf16_f32((ushort)(mu[w] >> 16))
                     + bf16_f32((ushort)(lu[w] >> 16));
            s += v0*v0 + v1*v1;
        }
    }
    Zp[idx] = s;
}

__global__ void k_psq1(const float* __restrict__ Zp, float* __restrict__ psq) {
    int idx = blockIdx.x*256 + threadIdx.x;   // exactly 32*2304
    int b = idx / P1, p = idx % P1;
    int y = p / 48, x = p % 48;
    const float* zb = Zp + (size_t)b*PLANE1;
    float s = 0.f;
    #pragma unroll
    for (int r = 0; r < 3; ++r)
        #pragma unroll
        for (int c = 0; c < 3; ++c) s += zb[(y+r)*50 + x + c];
    psq[idx] = s;
}

// ===================== shifted-tap MFMA GEMM, LDS-staged B, 32x32x16 =====================
// Per K-chunk: stage the block's <=300-pixel window (3 splits) into LDS once;
// 9 taps read B-frags via ds_read_b128 (9x reuse).
// LDS px stride 44 ushorts (22 words, gcd(22,32)=2 -> 2-way = free; stride 40
// gave 2x conflict overhead in R9: 1.59e7 SQ_LDS_BANK_CONFLICT).
// MFMA 32x32x16 (1.2x pipe throughput vs 16x16x32, half the issue slots).
//   A: m=lane&31, k=(lane>>5)*8+j ; C/D: col=lane&31, row=(reg&3)+8*(reg>>2)+4*(lane>>5)
// 6 bf16-split products: hh, mh, lh (Xh) ; hm, mm (Xm) ; hl (Xl).
__global__ __launch_bounds__(256, 2) void k_gemm_mfma(
        const ushort* __restrict__ Wh, const ushort* __restrict__ Wm, const ushort* __restrict__ Wl,
        const ushort* __restrict__ Xh, const ushort* __restrict__ Xm, const ushort* __restrict__ Xl,
        const float* __restrict__ psq, const float* __restrict__ wsq, float* __restrict__ Dout,
        int M, int CP, int OW, int PW, int PLN, int Nper, int KB) {
    __shared__ ushort Bsm[39600];   // 79.2 KB: [3][300][44]

    int tid = threadIdx.x;
    int batch = blockIdx.x / KB;
    int kblk  = blockIdx.x % KB;
    int p0 = kblk*192; if (p0 + 192 > Nper) p0 = Nper - 192;   // overlap: dup writes identical
    int m0 = blockIdx.y*128; if (m0 + 128 > M)  m0 = M - 128;
    int lane = tid & 63, wid = tid >> 6;
    int wy = wid >> 1, wx = wid & 1;
    int half = lane >> 5, lp = lane & 31;

    int R0  = p0 / OW;
    int NR  = (p0 + 191) / OW + 2 - R0 + 1;    // rows incl. +2 tap halo (<=12)
    int NPX = NR * PW;                          // <= 300
    size_t gpix0 = (size_t)batch * PLN + (size_t)R0 * PW;

    // A row offsets: wave covers 64 rows = 2 m-tiles of 32
    int aoff[2];
    #pragma unroll
    for (int mt = 0; mt < 2; ++mt)
        aoff[mt] = (m0 + wy*64 + mt*32 + lp)*CP + half*8;
    // B pixel offsets: wave covers 96 cols = 3 n-tiles of 32
    int baseN[3];
    #pragma unroll
    for (int nt = 0; nt < 3; ++nt) {
        int p = p0 + wx*96 + nt*32 + lp;
        baseN[nt] = (p/OW - R0)*PW + (p % OW);
    }

    f32x16 acc[2][3];
    #pragma unroll
    for (int mt = 0; mt < 2; ++mt)
        #pragma unroll
        for (int nt = 0; nt < 3; ++nt)
            #pragma unroll
            for (int e = 0; e < 16; ++e) acc[mt][nt][e] = 0.f;

    int MC = M*CP;
    for (int c0 = 0; c0 < CP; c0 += 32) {
        __syncthreads();                        // protect prior chunk's reads
        int units = 12 * NPX;                   // 3 splits x 4 quads x NPX pixels
        for (int u = tid; u < units; u += 256) {
            int q  = u & 3;
            int rem = u >> 2;                   // sp*NPX + px
            int sp = rem / NPX, px = rem - sp*NPX;
            const ushort* Xs = (sp == 0) ? Xh : ((sp == 1) ? Xm : Xl);
            uint4 v = *(const uint4*)(Xs + (gpix0 + px)*CP + c0 + q*8);
            *(uint4*)&Bsm[sp*13200 + px*44 + q*8] = v;
        }
        __syncthreads();

        for (int r = 0; r < 3; ++r)
        for (int st = 0; st < 3; ++st) {
            int soffA = (r*3 + st)*MC + c0;
            int tpx = r*PW + st;                // tap pixel shift
            #pragma unroll
            for (int ks = 0; ks < 2; ++ks) {    // two K=16 steps per 32-ch chunk
                int co = ks*16 + half*8;
                bf16x8 af0[2], af1[2], af2[2];
                #pragma unroll
                for (int mt = 0; mt < 2; ++mt) {
                    int ao = soffA + aoff[mt] + ks*16;
                    af0[mt] = *(const bf16x8*)(Wh + ao);
                    af1[mt] = *(const bf16x8*)(Wm + ao);
                    af2[mt] = *(const bf16x8*)(Wl + ao);
                }
                bf16x8 bf[3];
                #pragma unroll
                for (int nt = 0; nt < 3; ++nt)
                    bf[nt] = *(const bf16x8*)&Bsm[(baseN[nt] + tpx)*44 + co];
                #pragma unroll
                for (int mt = 0; mt < 2; ++mt)
                    #pragma unroll
                    for (int nt = 0; nt < 3; ++nt)
                        acc[mt][nt] = __builtin_amdgcn_mfma_f32_32x32x16_bf16(af0[mt], bf[nt], acc[mt][nt], 0, 0, 0);
                #pragma unroll
                for (int mt = 0; mt < 2; ++mt)
                    #pragma unroll
                    for (int nt = 0; nt < 3; ++nt)
                        acc[mt][nt] = __builtin_amdgcn_mfma_f32_32x32x16_bf16(af1[mt], bf[nt], acc[mt][nt], 0, 0, 0);
                #pragma unroll
                for (int mt = 0; mt < 2; ++mt)
                    #pragma unroll
                    for (int nt = 0; nt < 3; ++nt)
                        acc[mt][nt] = __builtin_amdgcn_mfma_f32_32x32x16_bf16(af2[mt], bf[nt], acc[mt][nt], 0, 0, 0);
                #pragma unroll
                for (int nt = 0; nt < 3; ++nt)
                    bf[nt] = *(const bf16x8*)&Bsm[13200 + (baseN[nt] + tpx)*44 + co];
                #pragma unroll
                for (int mt = 0; mt < 2; ++mt)
                    #pragma unroll
                    for (int nt = 0; nt < 3; ++nt)
                        acc[mt][nt] = __builtin_amdgcn_mfma_f32_32x32x16_bf16(af0[mt], bf[nt], acc[mt][nt], 0, 0, 0);
                #pragma unroll
                for (int mt = 0; mt < 2; ++mt)
                    #pragma unroll
                    for (int nt = 0; nt < 3; ++nt)
                        acc[mt][nt] = __builtin_amdgcn_mfma_f32_32x32x16_bf16(af1[mt], bf[nt], acc[mt][nt], 0, 0, 0);
                #pragma unroll
                for (int nt = 0; nt < 3; ++nt)
                    bf[nt] = *(const bf16x8*)&Bsm[26400 + (baseN[nt] + tpx)*44 + co];
                #pragma unroll
                for (int mt = 0; mt < 2; ++mt)
                    #pragma unroll
                    for (int nt = 0; nt < 3; ++nt)
                        acc[mt][nt] = __builtin_amdgcn_mfma_f32_32x32x16_bf16(af0[mt], bf[nt], acc[mt][nt], 0, 0, 0);
            }
        }
    }

    // epilogue: C/D col=lane&31, row=(reg&3)+8*(reg>>2)+4*half
    #pragma unroll
    for (int mt = 0; mt < 2; ++mt) {
        #pragma unroll
        for (int nt = 0; nt < 3; ++nt) {
            int gn = p0 + wx*96 + nt*32 + lp;
            float ps = psq[batch*Nper + gn];
            size_t ob = (size_t)batch*M*Nper + gn;
            f32x16 a = acc[mt][nt];
            #pragma unroll
            for (int g = 0; g < 4; ++g) {
                int gmb = m0 + wy*64 + mt*32 + g*8 + half*4;
                float4 w4 = *(const float4*)&wsq[gmb];
                Dout[ob + (size_t)(gmb+0)*Nper] = sqrtf(fmaxf(ps + w4.x - 2.0f*a[g*4+0], 0.f));
                Dout[ob + (size_t)(gmb+1)*Nper] = sqrtf(fmaxf(ps + w4.y - 2.0f*a[g*4+1], 0.f));
                Dout[ob + (size_t)(gmb+2)*Nper] = sqrtf(fmaxf(ps + w4.z - 2.0f*a[g*4+2], 0.f));
                Dout[ob + (size_t)(gmb+3)*Nper] = sqrtf(fmaxf(ps + w4.w - 2.0f*a[g*4+3], 0.f));
            }
        }
    }
}

// ===================== triangle + sfm(2,2) after conv1 -> channel-last X2' splits =====================
__global__ void k_tri_sfm2(const float* __restrict__ D1, const float* __restrict__ thr2,
                           const float* __restrict__ w2, ushort* __restrict__ XH,
                           ushort* __restrict__ XM, ushort* __restrict__ XL) {
    int idx = blockIdx.x*256 + threadIdx.x;   // 32*576*32 = 589,824
    int oct = idx & 31;
    int rest = idx >> 5;                      // b*576 + q
    int q = rest % P2, b = rest / P2;
    int i = q / 24, j = q % 24;
    float thr = thr2[b], invw = 1.0f / w2[0];
    int base = (2*i)*48 + 2*j;
    ushort h[8], m[8], l[8];
    #pragma unroll
    for (int j8 = 0; j8 < 8; ++j8) {
        int c = oct*8 + j8;
        float v = 0.f;
        if (c < M1) {
            const float* src = D1 + ((size_t)b*M1 + c)*P1;
            float d00 = src[base], d01 = src[base+1], d10 = src[base+48], d11 = src[base+49];
            float t00 = d00 > thr ? 0.f : 1.f - d00*invw;
            float t01 = d01 > thr ? 0.f : 1.f - d01*invw;
            float t10 = d10 > thr ? 0.f : 1.f - d10*invw;
            float t11 = d11 > thr ? 0.f : 1.f - d11*invw;
            v = 0.25f*(0.9f*t00 + 0.93f*t01 + 0.96f*t10 + 0.99f*t11);
        }
        split3(v, h[j8], m[j8], l[j8]);
    }
    size_t ob = (size_t)rest * C2P + oct*8;
    uint4 ph, pm, pl;
    ph.x = (uint)h[0] | ((uint)h[1]<<16); ph.y = (uint)h[2] | ((uint)h[3]<<16);
    ph.z = (uint)h[4] | ((uint)h[5]<<16); ph.w = (uint)h[6] | ((uint)h[7]<<16);
    pm.x = (uint)m[0] | ((uint)m[1]<<16); pm.y = (uint)m[2] | ((uint)m[3]<<16);
    pm.z = (uint)m[4] | ((uint)m[5]<<16); pm.w = (uint)m[6] | ((uint)m[7]<<16);
    pl.x = (uint)l[0] | ((uint)l[1]<<16); pl.y = (uint)l[2] | ((uint)l[3]<<16);
    pl.z = (uint)l[4] | ((uint)l[5]<<16); pl.w = (uint)l[6] | ((uint)l[7]<<16);
    *(uint4*)&XH[ob] = ph; *(uint4*)&XM[ob] = pm; *(uint4*)&XL[ob] = pl;
}

__global__ void k_z2(const ushort* __restrict__ XH, const ushort* __restrict__ XM,
                     const ushort* __restrict__ XL, float* __restrict__ Z2) {
    int idx = blockIdx.x*256 + threadIdx.x;
    if (idx >= NB*P2) return;
    size_t base = (size_t)idx * C2P;
    float s = 0.f;
    for (int oct = 0; oct < 32; ++oct) {
        uint4 ph = *(const uint4*)&XH[base + oct*8];
        uint4 pm = *(const uint4*)&XM[base + oct*8];
        uint4 pl = *(const uint4*)&XL[base + oct*8];
        const uint* hu = (const uint*)&ph; const uint* mu = (const uint*)&pm;
        const uint* lu = (const uint*)&pl;
        #pragma unroll
        for (int w = 0; w < 4; ++w) {
            float v0 = bf16_f32((ushort)(hu[w] & 0xFFFF)) + bf16_f32((ushort)(mu[w] & 0xFFFF))
                     + bf16_f32((ushort)(lu[w] & 0xFFFF));
            float v1 = bf16_f32((ushort)(hu[w] >> 16)) + bf16_f32((ushort)(mu[w] >> 16))
                     + bf16_f32((ushort)(lu[w] >> 16));
            s += v0*v0 + v1*v1;
        }
    }
    Z2[idx] = s;
}

__global__ void k_psq2(const float* __restrict__ Z2, float* __restrict__ psq) {
    int idx = blockIdx.x*256 + threadIdx.x;
    if (idx >= NB*N2) return;
    int b = idx / N2, p = idx % N2;
    int y = p / 22, x = p % 22;
    const float* zb = Z2 + (size_t)b*P2;
    float s = 0.f;
    #pragma unroll
    for (int r = 0; r < 3; ++r)
        #pragma unroll
        for (int c = 0; c < 3; ++c) s += zb[(y+r)*24 + x + c];
    psq[idx] = s;
}

// ===================== triangle + FC =====================
__global__ void k_fc(const float* __restrict__ D2, const float* __restrict__ fcw,
                     const float* __restrict__ thr3, const float* __restrict__ w3,
                     float* __restrict__ out) {
    int tid = threadIdx.x, b = blockIdx.y;
    float thr = thr3[b];
    float invw = 1.0f / w3[0];
    const float* db = D2 + (size_t)b*FCN;
    float acc[10];
    #pragma unroll
    for (int o = 0; o < 10; ++o) acc[o] = 0.f;
    int base = blockIdx.x*2048;
    #pragma unroll
    for (int it = 0; it < 8; ++it) {
        int p = base + it*256 + tid;
        if (p < FCN) {
            float v = db[p];
            float tv = v > thr ? 0.f : 1.f - v*invw;
            #pragma unroll
            for (int o = 0; o < 10; ++o) acc[o] += tv * fcw[(size_t)o*FCN + p];
        }
    }
    #pragma unroll
    for (int o = 0; o < 10; ++o)
        #pragma unroll
        for (int off = 32; off; off >>= 1) acc[o] += __shfl_down(acc[o], off);
    __shared__ float red[4][10];
    int lane = tid & 63, wid = tid >> 6;
    if (lane == 0) {
        #pragma unroll
        for (int o = 0; o < 10; ++o) red[wid][o] = acc[o];
    }
    __syncthreads();
    if (tid < 10) {
        float s = red[0][tid] + red[1][tid] + red[2][tid] + red[3][tid];
        atomicAdd(&out[b*10 + tid], s);
    }
}

// ===================== launch =====================
extern "C" void kernel_launch(void* const* d_in, const int* in_sizes, int n_in,
                              void* d_out, int out_size, void* d_ws, size_t ws_size,
                              hipStream_t stream) {
    const float* x    = (const float*)d_in[0];
    const float* rgbw = (const float*)d_in[1];
    const float* gryw = (const float*)d_in[2];
    const float* c1w  = (const float*)d_in[3];
    const float* c2w  = (const float*)d_in[4];
    const float* fcw  = (const float*)d_in[5];
    const float* fcb  = (const float*)d_in[6];
    const float* w1   = (const float*)d_in[7];
    const float* w2   = (const float*)d_in[8];
    const float* w3   = (const float*)d_in[9];
    float* out = (float*)d_out;
    float* ws  = (float*)d_ws;

    float* Drgb  = ws + O_A;
    float* Dgray = ws + O_B;
    uint*  hist  = (uint*)(ws + O_HIST);
    uint2* state = (uint2*)(ws + O_STATE);
    float* thr   = ws + O_THR;

    // init threads: 65536 + 320 + 128 = 65,984 -> 258 blocks
    k_tables<<<258, 256, 0, stream>>>(ws, fcb, out);
    k_wsq<<<M1 + M2, 64, 0, stream>>>(c1w, c2w, ws);
    k_rgb_d<<<dim3(36, 32), 256, 0, stream>>>(x, rgbw, Drgb);
    k_gray_d<<<dim3(36, 32), 256, 0, stream>>>(x, gryw, Dgray);

    auto sel = [&](const float* dptr, int perBatch, uint2* st, float* thro, const float* wc) {
        const int shifts[3] = {21, 10, 0};
        const uint masks[3] = {0u, 0xFFE00000u, 0xFFFFFC00u};
        for (int p = 0; p < 3; ++p) {
            k_hist<<<dim3(32, 32), 256, 0, stream>>>(dptr, perBatch, hist, st, shifts[p], masks[p]);
            k_scan<<<32, 256, 0, stream>>>(hist, st, shifts[p], p == 2, thro, wc);
        }
    };

    sel(Drgb, ORGB*L1N, state + 0,  thr + 0,  w1);
    sel(Dgray, OGRAY*L1N, state + 32, thr + 32, w1);

    k_tri_sfm1<<<5000, 256, 0, stream>>>(Drgb, Dgray, thr + 0, thr + 32, w1,
        (ushort*)(ws + O_X1H), (ushort*)(ws + O_X1M), (ushort*)(ws + O_X1L));
    // W splits overlay the (now dead) Dgray region: 259,200 + 1,440,000 threads -> 6638 blocks
    k_splitw<<<6638, 256, 0, stream>>>(c1w, c2w, ws);
    k_z1<<<313, 256, 0, stream>>>((const ushort*)(ws + O_X1H), (const ushort*)(ws + O_X1M),
        (const ushort*)(ws + O_X1L), ws + O_ZP1);
    k_psq1<<<288, 256, 0, stream>>>(ws + O_ZP1, ws + O_PSQ1);

    float* D1 = ws + O_A;
    // gemm1: 12 n-blocks/batch x 32 batches, 2 m-tiles
    k_gemm_mfma<<<dim3(12*NB, 2), 256, 0, stream>>>(
        (const ushort*)(ws + O_W1H), (const ushort*)(ws + O_W1M), (const ushort*)(ws + O_W1L),
        (const ushort*)(ws + O_X1H), (const ushort*)(ws + O_X1M), (const ushort*)(ws + O_X1L),
        ws + O_PSQ1, ws + O_WSQ1, D1, M1, C1P, 48, 50, PLANE1, P1, 12);

    sel(D1, M1*P1, state + 64, thr + 64, w2);

    k_tri_sfm2<<<2304, 256, 0, stream>>>(D1, thr + 64, w2,
        (ushort*)(ws + O_X2H), (ushort*)(ws + O_X2M), (ushort*)(ws + O_X2L));
    k_z2<<<72, 256, 0, stream>>>((const ushort*)(ws + O_X2H), (const ushort*)(ws + O_X2M),
        (const ushort*)(ws + O_X2L), ws + O_Z2);
    k_psq2<<<61, 256, 0, stream>>>(ws + O_Z2, ws + O_PSQ2);

    float* D2 = ws + O_A;
    // gemm2: 3 n-blocks/batch x 32 batches, 5 m-tiles
    k_gemm_mfma<<<dim3(3*NB, 5), 256, 0, stream>>>(
        (const ushort*)(ws + O_W2H), (const ushort*)(ws + O_W2M), (const ushort*)(ws + O_W2L),
        (const ushort*)(ws + O_X2H), (const ushort*)(ws + O_X2M), (const ushort*)(ws + O_X2L),
        ws + O_PSQ2, ws + O_WSQ2, D2, M2, C2P, 22, 24, P2, N2, 3);

    sel(D2, FCN, state + 96, thr + 96, w3);

    k_fc<<<dim3(148, 32), 256, 0, stream>>>(D2, fcw, thr + 96, w3, out);
}

// Round 11
// 1079.862 us; speedup vs baseline: 1.4524x; 1.1000x over previous
//
#include <hip/hip_runtime.h>

typedef unsigned int uint;
typedef unsigned short ushort;

#define NB 32

// geometry
#define L1N 9216      // 96*96
#define ORGB 75
#define OGRAY 25
#define C1 100
#define C1P 128       // channel pad, layer-1 GEMM
#define PLANE1 2500   // 50*50 padded
#define P1 2304       // 48*48
#define M1 225
#define P2 576        // 24*24
#define M2 625
#define C2P 256       // channel pad, layer-2 GEMM (M1=225 -> 256)
#define N2 484        // 22*22
#define FCN 302500    // 625*484
#define FSL 1024      // fc p-slice

// exact ranks: ceil(percent*N) evaluated in fp64
#define KK0 345600u
#define KK1 115200u
#define KK2 207360u
#define KK3 121000u

// ---- workspace layout (float-element offsets) ----
constexpr size_t O_A     = 0;                       // Drgb 22,118,400 -> D1 16.6M -> D2 9.68M
constexpr size_t O_B     = 22118400;                // Dgray 7,372,800 ; W overlays after tri_sfm1
constexpr size_t O_W1H   = O_B;                     // 9*225*128 ushorts = 129,600 floats each
constexpr size_t O_W1M   = O_B + 129600;
constexpr size_t O_W1L   = O_B + 259200;
constexpr size_t O_W2H   = O_B + 388800;            // 9*625*256 ushorts = 720,000 floats each
constexpr size_t O_W2M   = O_B + 1108800;
constexpr size_t O_W2L   = O_B + 1828800;           // end 2,548,800 <= 7,372,800
constexpr size_t O_X     = 29491200;                // X' channel-last split planes
constexpr size_t O_X1H   = O_X;                     // 32*2500*128 ushorts = 5,120,000 floats each
constexpr size_t O_X1M   = O_X + 5120000;
constexpr size_t O_X1L   = O_X + 10240000;
constexpr size_t O_X2H   = O_X;                     // overlay: 32*576*256 ushorts = 2,359,296 floats
constexpr size_t O_X2M   = O_X + 2359296;
constexpr size_t O_X2L   = O_X + 4718592;
constexpr size_t O_HIST  = O_X + 15360000;          // 64 x 2048 uints = 131,072
constexpr size_t O_STATE = O_HIST + 131072;         // 128 uint2
constexpr size_t O_THR   = O_STATE + 256;
constexpr size_t O_WSQ1  = O_THR + 128;
constexpr size_t O_WSQ2  = O_WSQ1 + 256;
constexpr size_t O_ZP1   = O_WSQ2 + 640;            // 80,000
constexpr size_t O_PSQ1  = O_ZP1 + 80000;           // 73,728
constexpr size_t O_Z2    = O_PSQ1 + 73728;          // 18,432
constexpr size_t O_PSQ2  = O_Z2 + 18432;            // 15,488
constexpr size_t O_END   = O_PSQ2 + 15488;          // ~180.9 MB

// ---- bf16 helpers (RNE) ----
__device__ __forceinline__ ushort bf16_rne(float x) {
    uint u = __float_as_uint(x);
    uint r = u + 0x7FFFu + ((u >> 16) & 1u);
    return (ushort)(r >> 16);
}
__device__ __forceinline__ float bf16_f32(ushort h) {
    return __uint_as_float(((uint)h) << 16);
}
__device__ __forceinline__ void split3(float v, ushort& h, ushort& m, ushort& l) {
    h = bf16_rne(v);           float hf = bf16_f32(h);
    m = bf16_rne(v - hf);      float mf = bf16_f32(m);
    l = bf16_rne(v - hf - mf);
}

typedef __attribute__((ext_vector_type(8))) short bf16x8;
typedef __attribute__((ext_vector_type(4))) float f32x4;
typedef __attribute__((ext_vector_type(16))) float f32x16;

// ===================== init: zero hist, states, out=bias =====================
__global__ void k_tables(float* ws, const float* fcb, float* out) {
    int i = blockIdx.x*256 + threadIdx.x;
    if (i < 131072) { ((uint*)(ws + O_HIST))[i] = 0u; return; }
    i -= 131072;
    if (i < 320) { out[i] = fcb[i % 10]; return; }
    i -= 320;
    if (i < 128) {
        const uint kks[4] = {KK0, KK1, KK2, KK3};
        ((uint2*)(ws + O_STATE))[i] = make_uint2(0u, kks[i >> 5]);
    }
}

// ===================== per-row squared norms of conv weights =====================
__global__ void k_wsq(const float* c1w, const float* c2w, float* ws) {
    int o = blockIdx.x, lane = threadIdx.x;   // 64 threads
    const float* row; int K; float* dst;
    if (o < M1) { row = c1w + (size_t)o*900; K = 900; dst = ws + O_WSQ1 + o; }
    else { int oo = o - M1; row = c2w + (size_t)oo*2025; K = 2025; dst = ws + O_WSQ2 + oo; }
    float s = 0.f;
    for (int k = lane; k < K; k += 64) { float v = row[k]; s += v*v; }
    #pragma unroll
    for (int off = 32; off; off >>= 1) s += __shfl_down(s, off);
    if (lane == 0) *dst = s;
}

// ===================== split W into tap-major bf16 planes Wrs[9][M][C'] =====================
__global__ void k_splitw(const float* __restrict__ c1w, const float* __restrict__ c2w,
                         float* __restrict__ ws) {
    int i = blockIdx.x*256 + threadIdx.x;
    ushort h, m, l;
    if (i < 9*M1*C1P) {
        int rs = i / (M1*C1P), r2 = i % (M1*C1P);
        int mm = r2 / C1P, c = r2 % C1P;
        float x = (c < C1) ? c1w[(size_t)mm*900 + c*9 + rs] : 0.f;
        split3(x, h, m, l);
        ((ushort*)(ws + O_W1H))[i] = h;
        ((ushort*)(ws + O_W1M))[i] = m;
        ((ushort*)(ws + O_W1L))[i] = l;
        return;
    }
    i -= 9*M1*C1P;
    if (i < 9*M2*C2P) {
        int rs = i / (M2*C2P), r2 = i % (M2*C2P);
        int mm = r2 / C2P, c = r2 % C2P;
        float x = (c < M1) ? c2w[(size_t)mm*2025 + c*9 + rs] : 0.f;
        split3(x, h, m, l);
        ((ushort*)(ws + O_W2H))[i] = h;
        ((ushort*)(ws + O_W2M))[i] = m;
        ((ushort*)(ws + O_W2L))[i] = l;
    }
}

// ===================== stage 1: rgb distance =====================
__global__ void k_rgb_d(const float* __restrict__ x, const float* __restrict__ rgbw,
                        float* __restrict__ D) {
    __shared__ float lw[ORGB*3];
    __shared__ float lwsq[ORGB];
    int tid = threadIdx.x;
    if (tid < ORGB*3) lw[tid] = rgbw[tid];
    __syncthreads();
    if (tid < ORGB) {
        float a = lw[tid*3], b = lw[tid*3+1], c = lw[tid*3+2];
        lwsq[tid] = 25.0f*(a*a + b*b + c*c);
    }
    __syncthreads();
    int p = blockIdx.x*256 + tid;
    int b = blockIdx.y;
    int y = p / 96, xx = p % 96;
    const float* xb = x + (size_t)b*3*10000;
    float s1_0 = 0, s1_1 = 0, s1_2 = 0, s2 = 0;
    #pragma unroll
    for (int r = 0; r < 5; ++r)
        #pragma unroll
        for (int s = 0; s < 5; ++s) {
            int off = (y+r)*100 + (xx+s);
            float v0 = xb[off], v1 = xb[10000+off], v2 = xb[20000+off];
            s1_0 += v0; s1_1 += v1; s1_2 += v2;
            s2 += v0*v0 + v1*v1 + v2*v2;
        }
    float* Db = D + (size_t)b*ORGB*L1N + p;
    for (int o = 0; o < ORGB; ++o) {
        float dot = lw[o*3]*s1_0 + lw[o*3+1]*s1_1 + lw[o*3+2]*s1_2;
        float d2 = s2 + lwsq[o] - 2.0f*dot;
        Db[(size_t)o*L1N] = sqrtf(fmaxf(d2, 0.0f));
    }
}

// ===================== stage 1: gray distance =====================
__global__ void k_gray_d(const float* __restrict__ x, const float* __restrict__ gw,
                         float* __restrict__ D) {
    __shared__ float lw[625];
    __shared__ float lwsq[25];
    int tid = threadIdx.x;
    for (int i = tid; i < 625; i += 256) lw[i] = gw[i];
    __syncthreads();
    if (tid < 25) {
        float s = 0.f;
        for (int k = 0; k < 25; ++k) { float v = lw[tid*25+k]; s += v*v; }
        lwsq[tid] = s;
    }
    __syncthreads();
    int p = blockIdx.x*256 + tid;
    int b = blockIdx.y;
    int y = p / 96, xx = p % 96;
    const float* xb = x + (size_t)b*3*10000;
    float pv[25]; float psum = 0.f;
    #pragma unroll
    for (int r = 0; r < 5; ++r)
        #pragma unroll
        for (int s = 0; s < 5; ++s) {
            int off = (y+r)*100 + (xx+s);
            float g = 0.2989f*xb[off] + 0.587f*xb[10000+off] + 0.114f*xb[20000+off];
            pv[r*5+s] = g; psum += g*g;
        }
    float* Db = D + (size_t)b*OGRAY*L1N + p;
    for (int o = 0; o < 25; ++o) {
        float dot = 0.f;
        #pragma unroll
        for (int k = 0; k < 25; ++k) dot += lw[o*25+k]*pv[k];
        float d2 = psum + lwsq[o] - 2.0f*dot;
        Db[(size_t)o*L1N] = sqrtf(fmaxf(d2, 0.0f));
    }
}

// ===================== exact rank selection: histogram pass (dual-source, early-exit) ==========
__global__ void k_hist(const float* __restrict__ dA, const float* __restrict__ dB,
                       int perA, int perB, int nA, uint* __restrict__ hist,
                       const uint2* __restrict__ state, int shift, uint pmask) {
    int b = blockIdx.y;
    uint2 st = state[b];
    if (st.y == 0u) return;              // threshold already resolved (cap bound)
    __shared__ uint lh[2048];
    int tid = threadIdx.x;
    for (int i = tid; i < 2048; i += 256) lh[i] = 0u;
    __syncthreads();
    const float* db; int per;
    if (b < nA) { db = dA + (size_t)b*perA; per = perA; }
    else        { db = dB + (size_t)(b - nA)*perB; per = perB; }
    uint pref = st.x;
    for (int i = blockIdx.x*256 + tid; i < per; i += 256*32) {
        uint bits = __float_as_uint(db[i]);
        if ((bits & pmask) == pref)
            atomicAdd(&lh[(bits >> shift) & 2047u], 1u);
    }
    __syncthreads();
    uint* hb = hist + (size_t)b*2048;
    for (int i = tid; i < 2048; i += 256) {
        uint v = lh[i];
        if (v) atomicAdd(&hb[i], v);
    }
}

// ===================== selection: scan + state update (+zero hist, early-exit) =================
__global__ void k_scan(uint* __restrict__ hist, uint2* __restrict__ state, int shift,
                       int isFinal, float* __restrict__ thr_out, const float* __restrict__ wcap) {
    __shared__ uint ss[256];
    int b = blockIdx.x, t = threadIdx.x;
    uint rank0 = state[b].y;
    if (rank0 == 0u) return;             // done in an earlier pass; hist already zero
    uint* hb = hist + (size_t)b*2048;
    uint bins[8]; uint seg = 0;
    #pragma unroll
    for (int i = 0; i < 8; ++i) { bins[i] = hb[t*8+i]; seg += bins[i]; }
    ss[t] = seg;
    __syncthreads();
    for (int off = 1; off < 256; off <<= 1) {
        uint add = (t >= off) ? ss[t-off] : 0u;
        __syncthreads();
        ss[t] += add;
        __syncthreads();
    }
    uint incl = ss[t], excl = incl - seg;
    uint rank = rank0;
    if (excl < rank && rank <= incl) {
        uint c = excl;
        #pragma unroll
        for (int i = 0; i < 8; ++i) {
            c += bins[i];
            if (c >= rank) {
                uint bin = (uint)(t*8+i);
                uint pref = state[b].x | (bin << shift);
                float w = wcap[0];
                if (isFinal) {
                    thr_out[b] = fminf(__uint_as_float(pref), w);
                } else if (__uint_as_float(pref) >= w) {
                    // bin lower bound >= w  =>  kth smallest >= w  =>  thr = w exactly
                    thr_out[b] = w;
                    state[b] = make_uint2(pref, 0u);   // sentinel: skip remaining passes
                } else {
                    state[b] = make_uint2(pref, rank - (c - bins[i]));
                }
                break;
            }
        }
    }
    __syncthreads();
    #pragma unroll
    for (int i = 0; i < 8; ++i) hb[t*8+i] = 0u;
}

// ===================== triangle + concat + sfm(2,2) -> channel-last X1' splits (+Zp) ===========
__global__ void k_tri_sfm1(const float* __restrict__ Drgb, const float* __restrict__ Dgray,
                           const float* __restrict__ thrA, const float* __restrict__ thrB,
                           const float* __restrict__ w1, ushort* __restrict__ XH,
                           ushort* __restrict__ XM, ushort* __restrict__ XL,
                           float* __restrict__ Zp) {
    int idx = blockIdx.x*256 + threadIdx.x;   // 32*2500*16 = 1,280,000
    int oct = idx & 15;
    int rest = idx >> 4;                      // b*2500 + q
    int q = rest % PLANE1, b = rest / PLANE1;
    int pi = q / 50, pj = q % 50;
    bool border = (pi == 0 || pi == 49 || pj == 0 || pj == 49);
    float invw = 1.0f / w1[0];
    float tA = thrA[b], tB = thrB[b];
    int base = (2*(pi-1))*96 + 2*(pj-1);
    ushort h[8], m[8], l[8];
    float vs = 0.f;
    #pragma unroll
    for (int j8 = 0; j8 < 8; ++j8) {
        int c = oct*8 + j8;
        float v = 0.f;
        if (!border && c < C1) {
            const float* src; float thr;
            if (c < ORGB) { src = Drgb + ((size_t)b*ORGB + c)*L1N; thr = tA; }
            else          { src = Dgray + ((size_t)b*OGRAY + (c-ORGB))*L1N; thr = tB; }
            float d00 = src[base], d01 = src[base+1], d10 = src[base+96], d11 = src[base+97];
            float t00 = d00 > thr ? 0.f : 1.f - d00*invw;
            float t01 = d01 > thr ? 0.f : 1.f - d01*invw;
            float t10 = d10 > thr ? 0.f : 1.f - d10*invw;
            float t11 = d11 > thr ? 0.f : 1.f - d11*invw;
            v = 0.25f*(0.9f*t00 + 0.93f*t01 + 0.96f*t10 + 0.99f*t11);
        }
        vs += v*v;
        split3(v, h[j8], m[j8], l[j8]);
    }
    size_t ob = (size_t)rest * C1P + oct*8;
    uint4 ph, pm, pl;
    ph.x = (uint)h[0] | ((uint)h[1]<<16); ph.y = (uint)h[2] | ((uint)h[3]<<16);
    ph.z = (uint)h[4] | ((uint)h[5]<<16); ph.w = (uint)h[6] | ((uint)h[7]<<16);
    pm.x = (uint)m[0] | ((uint)m[1]<<16); pm.y = (uint)m[2] | ((uint)m[3]<<16);
    pm.z = (uint)m[4] | ((uint)m[5]<<16); pm.w = (uint)m[6] | ((uint)m[7]<<16);
    pl.x = (uint)l[0] | ((uint)l[1]<<16); pl.y = (uint)l[2] | ((uint)l[3]<<16);
    pl.z = (uint)l[4] | ((uint)l[5]<<16); pl.w = (uint)l[6] | ((uint)l[7]<<16);
    *(uint4*)&XH[ob] = ph; *(uint4*)&XM[ob] = pm; *(uint4*)&XL[ob] = pl;
    // fused Zp: sum of v^2 over the 16 octs (16-lane shuffle reduce)
    #pragma unroll
    for (int off = 8; off; off >>= 1) vs += __shfl_down(vs, off);
    if (oct == 0) Zp[rest] = vs;
}

__global__ void k_psq1(const float* __restrict__ Zp, float* __restrict__ psq) {
    int idx = blockIdx.x*256 + threadIdx.x;   // exactly 32*2304
    int b = idx / P1, p = idx % P1;
    int y = p / 48, x = p % 48;
    const float* zb = Zp + (size_t)b*PLANE1;
    float s = 0.f;
    #pragma unroll
    for (int r = 0; r < 3; ++r)
        #pragma unroll
        for (int c = 0; c < 3; ++c) s += zb[(y+r)*50 + x + c];
    psq[idx] = s;
}

// ===================== shifted-tap MFMA GEMM, LDS-staged B, 32x32x16 =====================
__global__ __launch_bounds__(256, 2) void k_gemm_mfma(
        const ushort* __restrict__ Wh, const ushort* __restrict__ Wm, const ushort* __restrict__ Wl,
        const ushort* __restrict__ Xh, const ushort* __restrict__ Xm, const ushort* __restrict__ Xl,
        const float* __restrict__ psq, const float* __restrict__ wsq, float* __restrict__ Dout,
        int M, int CP, int OW, int PW, int PLN, int Nper, int KB) {
    __shared__ ushort Bsm[39600];   // 79.2 KB: [3][300][44]

    int tid = threadIdx.x;
    int batch = blockIdx.x / KB;
    int kblk  = blockIdx.x % KB;
    int p0 = kblk*192; if (p0 + 192 > Nper) p0 = Nper - 192;   // overlap: dup writes identical
    int m0 = blockIdx.y*128; if (m0 + 128 > M)  m0 = M - 128;
    int lane = tid & 63, wid = tid >> 6;
    int wy = wid >> 1, wx = wid & 1;
    int half = lane >> 5, lp = lane & 31;

    int R0  = p0 / OW;
    int NR  = (p0 + 191) / OW + 2 - R0 + 1;    // rows incl. +2 tap halo (<=12)
    int NPX = NR * PW;                          // <= 300
    size_t gpix0 = (size_t)batch * PLN + (size_t)R0 * PW;

    int aoff[2];
    #pragma unroll
    for (int mt = 0; mt < 2; ++mt)
        aoff[mt] = (m0 + wy*64 + mt*32 + lp)*CP + half*8;
    int baseN[3];
    #pragma unroll
    for (int nt = 0; nt < 3; ++nt) {
        int p = p0 + wx*96 + nt*32 + lp;
        baseN[nt] = (p/OW - R0)*PW + (p % OW);
    }

    f32x16 acc[2][3];
    #pragma unroll
    for (int mt = 0; mt < 2; ++mt)
        #pragma unroll
        for (int nt = 0; nt < 3; ++nt)
            #pragma unroll
            for (int e = 0; e < 16; ++e) acc[mt][nt][e] = 0.f;

    int MC = M*CP;
    for (int c0 = 0; c0 < CP; c0 += 32) {
        __syncthreads();                        // protect prior chunk's reads
        int units = 12 * NPX;                   // 3 splits x 4 quads x NPX pixels
        for (int u = tid; u < units; u += 256) {
            int q  = u & 3;
            int rem = u >> 2;                   // sp*NPX + px
            int sp = rem / NPX, px = rem - sp*NPX;
            const ushort* Xs = (sp == 0) ? Xh : ((sp == 1) ? Xm : Xl);
            uint4 v = *(const uint4*)(Xs + (gpix0 + px)*CP + c0 + q*8);
            *(uint4*)&Bsm[sp*13200 + px*44 + q*8] = v;
        }
        __syncthreads();

        for (int r = 0; r < 3; ++r)
        for (int st = 0; st < 3; ++st) {
            int soffA = (r*3 + st)*MC + c0;
            int tpx = r*PW + st;                // tap pixel shift
            #pragma unroll
            for (int ks = 0; ks < 2; ++ks) {    // two K=16 steps per 32-ch chunk
                int co = ks*16 + half*8;
                bf16x8 af0[2], af1[2], af2[2];
                #pragma unroll
                for (int mt = 0; mt < 2; ++mt) {
                    int ao = soffA + aoff[mt] + ks*16;
                    af0[mt] = *(const bf16x8*)(Wh + ao);
                    af1[mt] = *(const bf16x8*)(Wm + ao);
                    af2[mt] = *(const bf16x8*)(Wl + ao);
                }
                bf16x8 bf[3];
                #pragma unroll
                for (int nt = 0; nt < 3; ++nt)
                    bf[nt] = *(const bf16x8*)&Bsm[(baseN[nt] + tpx)*44 + co];
                #pragma unroll
                for (int mt = 0; mt < 2; ++mt)
                    #pragma unroll
                    for (int nt = 0; nt < 3; ++nt)
                        acc[mt][nt] = __builtin_amdgcn_mfma_f32_32x32x16_bf16(af0[mt], bf[nt], acc[mt][nt], 0, 0, 0);
                #pragma unroll
                for (int mt = 0; mt < 2; ++mt)
                    #pragma unroll
                    for (int nt = 0; nt < 3; ++nt)
                        acc[mt][nt] = __builtin_amdgcn_mfma_f32_32x32x16_bf16(af1[mt], bf[nt], acc[mt][nt], 0, 0, 0);
                #pragma unroll
                for (int mt = 0; mt < 2; ++mt)
                    #pragma unroll
                    for (int nt = 0; nt < 3; ++nt)
                        acc[mt][nt] = __builtin_amdgcn_mfma_f32_32x32x16_bf16(af2[mt], bf[nt], acc[mt][nt], 0, 0, 0);
                #pragma unroll
                for (int nt = 0; nt < 3; ++nt)
                    bf[nt] = *(const bf16x8*)&Bsm[13200 + (baseN[nt] + tpx)*44 + co];
                #pragma unroll
                for (int mt = 0; mt < 2; ++mt)
                    #pragma unroll
                    for (int nt = 0; nt < 3; ++nt)
                        acc[mt][nt] = __builtin_amdgcn_mfma_f32_32x32x16_bf16(af0[mt], bf[nt], acc[mt][nt], 0, 0, 0);
                #pragma unroll
                for (int mt = 0; mt < 2; ++mt)
                    #pragma unroll
                    for (int nt = 0; nt < 3; ++nt)
                        acc[mt][nt] = __builtin_amdgcn_mfma_f32_32x32x16_bf16(af1[mt], bf[nt], acc[mt][nt], 0, 0, 0);
                #pragma unroll
                for (int nt = 0; nt < 3; ++nt)
                    bf[nt] = *(const bf16x8*)&Bsm[26400 + (baseN[nt] + tpx)*44 + co];
                #pragma unroll
                for (int mt = 0; mt < 2; ++mt)
                    #pragma unroll
                    for (int nt = 0; nt < 3; ++nt)
                        acc[mt][nt] = __builtin_amdgcn_mfma_f32_32x32x16_bf16(af0[mt], bf[nt], acc[mt][nt], 0, 0, 0);
            }
        }
    }

    // epilogue: C/D col=lane&31, row=(reg&3)+8*(reg>>2)+4*half
    #pragma unroll
    for (int mt = 0; mt < 2; ++mt) {
        #pragma unroll
        for (int nt = 0; nt < 3; ++nt) {
            int gn = p0 + wx*96 + nt*32 + lp;
            float ps = psq[batch*Nper + gn];
            size_t ob = (size_t)batch*M*Nper + gn;
            f32x16 a = acc[mt][nt];
            #pragma unroll
            for (int g = 0; g < 4; ++g) {
                int gmb = m0 + wy*64 + mt*32 + g*8 + half*4;
                float4 w4 = *(const float4*)&wsq[gmb];
                Dout[ob + (size_t)(gmb+0)*Nper] = sqrtf(fmaxf(ps + w4.x - 2.0f*a[g*4+0], 0.f));
                Dout[ob + (size_t)(gmb+1)*Nper] = sqrtf(fmaxf(ps + w4.y - 2.0f*a[g*4+1], 0.f));
                Dout[ob + (size_t)(gmb+2)*Nper] = sqrtf(fmaxf(ps + w4.z - 2.0f*a[g*4+2], 0.f));
                Dout[ob + (size_t)(gmb+3)*Nper] = sqrtf(fmaxf(ps + w4.w - 2.0f*a[g*4+3], 0.f));
            }
        }
    }
}

// ===================== triangle + sfm(2,2) after conv1 -> channel-last X2' splits (+Z2) ========
__global__ void k_tri_sfm2(const float* __restrict__ D1, const float* __restrict__ thr2,
                           const float* __restrict__ w2, ushort* __restrict__ XH,
                           ushort* __restrict__ XM, ushort* __restrict__ XL,
                           float* __restrict__ Z2) {
    int idx = blockIdx.x*256 + threadIdx.x;   // 32*576*32 = 589,824
    int oct = idx & 31;
    int rest = idx >> 5;                      // b*576 + q
    int q = rest % P2, b = rest / P2;
    int i = q / 24, j = q % 24;
    float thr = thr2[b], invw = 1.0f / w2[0];
    int base = (2*i)*48 + 2*j;
    ushort h[8], m[8], l[8];
    float vs = 0.f;
    #pragma unroll
    for (int j8 = 0; j8 < 8; ++j8) {
        int c = oct*8 + j8;
        float v = 0.f;
        if (c < M1) {
            const float* src = D1 + ((size_t)b*M1 + c)*P1;
            float d00 = src[base], d01 = src[base+1], d10 = src[base+48], d11 = src[base+49];
            float t00 = d00 > thr ? 0.f : 1.f - d00*invw;
            float t01 = d01 > thr ? 0.f : 1.f - d01*invw;
            float t10 = d10 > thr ? 0.f : 1.f - d10*invw;
            float t11 = d11 > thr ? 0.f : 1.f - d11*invw;
            v = 0.25f*(0.9f*t00 + 0.93f*t01 + 0.96f*t10 + 0.99f*t11);
        }
        vs += v*v;
        split3(v, h[j8], m[j8], l[j8]);
    }
    size_t ob = (size_t)rest * C2P + oct*8;
    uint4 ph, pm, pl;
    ph.x = (uint)h[0] | ((uint)h[1]<<16); ph.y = (uint)h[2] | ((uint)h[3]<<16);
    ph.z = (uint)h[4] | ((uint)h[5]<<16); ph.w = (uint)h[6] | ((uint)h[7]<<16);
    pm.x = (uint)m[0] | ((uint)m[1]<<16); pm.y = (uint)m[2] | ((uint)m[3]<<16);
    pm.z = (uint)m[4] | ((uint)m[5]<<16); pm.w = (uint)m[6] | ((uint)m[7]<<16);
    pl.x = (uint)l[0] | ((uint)l[1]<<16); pl.y = (uint)l[2] | ((uint)l[3]<<16);
    pl.z = (uint)l[4] | ((uint)l[5]<<16); pl.w = (uint)l[6] | ((uint)l[7]<<16);
    *(uint4*)&XH[ob] = ph; *(uint4*)&XM[ob] = pm; *(uint4*)&XL[ob] = pl;
    // fused Z2: sum of v^2 over 32 octs
    #pragma unroll
    for (int off = 16; off; off >>= 1) vs += __shfl_down(vs, off);
    if (oct == 0) Z2[rest] = vs;
}

__global__ void k_psq2(const float* __restrict__ Z2, float* __restrict__ psq) {
    int idx = blockIdx.x*256 + threadIdx.x;
    if (idx >= NB*N2) return;
    int b = idx / N2, p = idx % N2;
    int y = p / 22, x = p % 22;
    const float* zb = Z2 + (size_t)b*P2;
    float s = 0.f;
    #pragma unroll
    for (int r = 0; r < 3; ++r)
        #pragma unroll
        for (int c = 0; c < 3; ++c) s += zb[(y+r)*24 + x + c];
    psq[idx] = s;
}

// ===================== triangle + FC: p-slice blocks, fcw staged in LDS (read once) ============
__global__ void k_fc(const float* __restrict__ D2, const float* __restrict__ fcw,
                     const float* __restrict__ thr3, const float* __restrict__ w3,
                     float* __restrict__ out) {
    __shared__ float fl[10*FSL];      // 40 KB
    __shared__ float red[4][10];
    int tid = threadIdx.x;
    int p0 = blockIdx.x*FSL;
    int n = FCN - p0; if (n > FSL) n = FSL;
    for (int i = tid; i < 10*FSL; i += 256) {
        int o = i / FSL, j = i - o*FSL;
        fl[i] = (j < n) ? fcw[(size_t)o*FCN + p0 + j] : 0.f;
    }
    __syncthreads();
    float invw = 1.0f / w3[0];
    int lane = tid & 63, wid = tid >> 6;
    for (int b = 0; b < NB; ++b) {
        float thr = thr3[b];
        float acc[10];
        #pragma unroll
        for (int o = 0; o < 10; ++o) acc[o] = 0.f;
        const float* db = D2 + (size_t)b*FCN + p0;
        #pragma unroll
        for (int k = 0; k < 4; ++k) {
            int j = k*256 + tid;
            if (j < n) {
                float v = db[j];
                float tv = v > thr ? 0.f : 1.f - v*invw;
                #pragma unroll
                for (int o = 0; o < 10; ++o) acc[o] += tv * fl[o*FSL + j];
            }
        }
        #pragma unroll
        for (int o = 0; o < 10; ++o)
            #pragma unroll
            for (int off = 32; off; off >>= 1) acc[o] += __shfl_down(acc[o], off);
        if (lane == 0) {
            #pragma unroll
            for (int o = 0; o < 10; ++o) red[wid][o] = acc[o];
        }
        __syncthreads();
        if (tid < 10) {
            float s = red[0][tid] + red[1][tid] + red[2][tid] + red[3][tid];
            atomicAdd(&out[b*10 + tid], s);
        }
        __syncthreads();
    }
}

// ===================== launch =====================
extern "C" void kernel_launch(void* const* d_in, const int* in_sizes, int n_in,
                              void* d_out, int out_size, void* d_ws, size_t ws_size,
                              hipStream_t stream) {
    const float* x    = (const float*)d_in[0];
    const float* rgbw = (const float*)d_in[1];
    const float* gryw = (const float*)d_in[2];
    const float* c1w  = (const float*)d_in[3];
    const float* c2w  = (const float*)d_in[4];
    const float* fcw  = (const float*)d_in[5];
    const float* fcb  = (const float*)d_in[6];
    const float* w1   = (const float*)d_in[7];
    const float* w2   = (const float*)d_in[8];
    const float* w3   = (const float*)d_in[9];
    float* out = (float*)d_out;
    float* ws  = (float*)d_ws;

    float* Drgb  = ws + O_A;
    float* Dgray = ws + O_B;
    uint*  hist  = (uint*)(ws + O_HIST);
    uint2* state = (uint2*)(ws + O_STATE);
    float* thr   = ws + O_THR;

    // init threads: 131072 + 320 + 128 = 131,520 -> 514 blocks
    k_tables<<<514, 256, 0, stream>>>(ws, fcb, out);
    k_wsq<<<M1 + M2, 64, 0, stream>>>(c1w, c2w, ws);
    k_rgb_d<<<dim3(36, 32), 256, 0, stream>>>(x, rgbw, Drgb);
    k_gray_d<<<dim3(36, 32), 256, 0, stream>>>(x, gryw, Dgray);

    const int shifts[3] = {21, 10, 0};
    const uint masks[3] = {0u, 0xFFE00000u, 0xFFFFFC00u};

    // merged layer-1 selection: rgb (state 0-31) + gray (state 32-63), both capped by w1
    for (int p = 0; p < 3; ++p) {
        k_hist<<<dim3(32, 64), 256, 0, stream>>>(Drgb, Dgray, ORGB*L1N, OGRAY*L1N, 32,
                                                 hist, state, shifts[p], masks[p]);
        k_scan<<<64, 256, 0, stream>>>(hist, state, shifts[p], p == 2, thr, w1);
    }

    k_tri_sfm1<<<5000, 256, 0, stream>>>(Drgb, Dgray, thr + 0, thr + 32, w1,
        (ushort*)(ws + O_X1H), (ushort*)(ws + O_X1M), (ushort*)(ws + O_X1L), ws + O_ZP1);
    k_splitw<<<6638, 256, 0, stream>>>(c1w, c2w, ws);
    k_psq1<<<288, 256, 0, stream>>>(ws + O_ZP1, ws + O_PSQ1);

    float* D1 = ws + O_A;
    k_gemm_mfma<<<dim3(12*NB, 2), 256, 0, stream>>>(
        (const ushort*)(ws + O_W1H), (const ushort*)(ws + O_W1M), (const ushort*)(ws + O_W1L),
        (const ushort*)(ws + O_X1H), (const ushort*)(ws + O_X1M), (const ushort*)(ws + O_X1L),
        ws + O_PSQ1, ws + O_WSQ1, D1, M1, C1P, 48, 50, PLANE1, P1, 12);

    for (int p = 0; p < 3; ++p) {
        k_hist<<<dim3(32, 32), 256, 0, stream>>>(D1, D1, M1*P1, M1*P1, 32,
                                                 hist, state + 64, shifts[p], masks[p]);
        k_scan<<<32, 256, 0, stream>>>(hist, state + 64, shifts[p], p == 2, thr + 64, w2);
    }

    k_tri_sfm2<<<2304, 256, 0, stream>>>(D1, thr + 64, w2,
        (ushort*)(ws + O_X2H), (ushort*)(ws + O_X2M), (ushort*)(ws + O_X2L), ws + O_Z2);
    k_psq2<<<61, 256, 0, stream>>>(ws + O_Z2, ws + O_PSQ2);

    float* D2 = ws + O_A;
    k_gemm_mfma<<<dim3(3*NB, 5), 256, 0, stream>>>(
        (const ushort*)(ws + O_W2H), (const ushort*)(ws + O_W2M), (const ushort*)(ws + O_W2L),
        (const ushort*)(ws + O_X2H), (const ushort*)(ws + O_X2M), (const ushort*)(ws + O_X2L),
        ws + O_PSQ2, ws + O_WSQ2, D2, M2, C2P, 22, 24, P2, N2, 3);

    for (int p = 0; p < 3; ++p) {
        k_hist<<<dim3(32, 32), 256, 0, stream>>>(D2, D2, FCN, FCN, 32,
                                                 hist, state + 96, shifts[p], masks[p]);
        k_scan<<<32, 256, 0, stream>>>(hist, state + 96, shifts[p], p == 2, thr + 96, w3);
    }

    // FC: 296 p-slice blocks, batches looped inside (fcw read once)
    k_fc<<<(FCN + FSL - 1)/FSL, 256, 0, stream>>>(D2, fcw, thr + 96, w3, out);
}